// Round 6
// baseline (2706.828 us; speedup 1.0000x reference)
//
#include <hip/hip_runtime.h>
#include <hip/hip_cooperative_groups.h>
#include <math.h>

namespace cg = cooperative_groups;

#define HIDDEN 512
#define WINDOW 24
#define KSZ 3
#define BATCH 2048
#define L_IN 514
#define H4 2048
#define LDT 40                    // padded LDS row stride (shorts) for 32-k tiles
#define BH (BATCH * HIDDEN)

typedef short short8 __attribute__((ext_vector_type(8)));
typedef float floatx4 __attribute__((ext_vector_type(4)));

__device__ __forceinline__ floatx4 mfma16(short8 a, short8 b, floatx4 c) {
    return __builtin_amdgcn_mfma_f32_16x16x32_bf16(a, b, c, 0, 0, 0);
}
__device__ __forceinline__ unsigned short f2bf(float x) {
    union { float f; unsigned u; } v; v.f = x;
    unsigned r = v.u + 0x7fff + ((v.u >> 16) & 1);   // RTNE
    return (unsigned short)(r >> 16);
}
__device__ __forceinline__ float bf2f(unsigned short u) {
    union { unsigned u; float f; } v; v.u = ((unsigned)u) << 16;
    return v.f;
}
__device__ __forceinline__ float sigmoidf(float x) { return 1.f / (1.f + expf(-x)); }

// ---------------------------------------------------------------------------
// cvt5: fp32 -> bf16 for Wd, Ud, Whh, d_init, s_init
// ---------------------------------------------------------------------------
__global__ void cvt5_kernel(const float* __restrict__ s0, unsigned short* __restrict__ d0,
                            const float* __restrict__ s1, unsigned short* __restrict__ d1,
                            const float* __restrict__ s2, unsigned short* __restrict__ d2,
                            const float* __restrict__ s3, unsigned short* __restrict__ d3,
                            const float* __restrict__ s4, unsigned short* __restrict__ d4) {
    const int g = blockIdx.x * blockDim.x + threadIdx.x;   // one float4 per thread
    const float* src; unsigned short* dst; int off;
    if      (g < 131072) { src = s0; dst = d0; off = g; }
    else if (g < 196608) { src = s1; dst = d1; off = g - 131072; }
    else if (g < 458752) { src = s2; dst = d2; off = g - 196608; }
    else if (g < 720896) { src = s3; dst = d3; off = g - 458752; }
    else if (g < 983040) { src = s4; dst = d4; off = g - 720896; }
    else return;
    float4 v = ((const float4*)src)[off];
    uint2 u;
    u.x = (unsigned)f2bf(v.x) | ((unsigned)f2bf(v.y) << 16);
    u.y = (unsigned)f2bf(v.z) | ((unsigned)f2bf(v.w) << 16);
    ((uint2*)dst)[off] = u;
}

// ---------------------------------------------------------------------------
// conv1d(2->24, k=3, valid) + bias + relu -> Htb bf16 [t][b][i]
// ---------------------------------------------------------------------------
__global__ void conv_kernel(const float* __restrict__ Z, const float* __restrict__ conv_w,
                            const float* __restrict__ conv_b,
                            unsigned int* __restrict__ Htu) {
    __shared__ float cw[WINDOW * 6];
    __shared__ float cb[WINDOW];
    const int b = blockIdx.x;
    if (threadIdx.x < WINDOW * 6) cw[threadIdx.x] = conv_w[threadIdx.x];
    if (threadIdx.x < WINDOW) cb[threadIdx.x] = conv_b[threadIdx.x];
    __syncthreads();
    const float* z0 = Z + (size_t)b * L_IN;
    const float* z1 = z0 + (size_t)BATCH * L_IN;
    const int i0 = threadIdx.x * 2;
    const float a0 = z0[i0], a1 = z0[i0 + 1], a2 = z0[i0 + 2], a3 = z0[i0 + 3];
    const float c0 = z1[i0], c1 = z1[i0 + 1], c2 = z1[i0 + 2], c3 = z1[i0 + 3];
#pragma unroll
    for (int o = 0; o < WINDOW; ++o) {
        const float* wc = cw + o * 6;
        float v0 = fmaxf(cb[o] + a0 * wc[0] + a1 * wc[1] + a2 * wc[2]
                               + c0 * wc[3] + c1 * wc[4] + c2 * wc[5], 0.f);
        float v1 = fmaxf(cb[o] + a1 * wc[0] + a2 * wc[1] + a3 * wc[2]
                               + c1 * wc[3] + c2 * wc[4] + c3 * wc[5], 0.f);
        Htu[((size_t)o * BATCH + b) * 256 + threadIdx.x] =
            (unsigned)f2bf(v0) | ((unsigned)f2bf(v1) << 16);
    }
}

// ---------------------------------------------------------------------------
// hw[t][b] = H_t[b,:] . w[24:]
// ---------------------------------------------------------------------------
__global__ void hw_kernel(const unsigned short* __restrict__ Htb,
                          const float* __restrict__ w, float* __restrict__ hw) {
    const int row = blockIdx.x * 4 + (threadIdx.x >> 6);
    const int lane = threadIdx.x & 63;
    short8 v = *(const short8*)(Htb + (size_t)row * HIDDEN + lane * 8);
    float acc = 0.f;
#pragma unroll
    for (int j = 0; j < 8; ++j)
        acc += bf2f((unsigned short)v[j]) * w[WINDOW + lane * 8 + j];
    for (int m = 32; m; m >>= 1) acc += __shfl_xor(acc, m, 64);
    if (lane == 0) hw[row] = acc;
}

// ---------------------------------------------------------------------------
// Gb = Htb[49152 x 512] @ Udb^T  (bf16 out)
// ---------------------------------------------------------------------------
__global__ __launch_bounds__(256) void g_gemm_mfma(const unsigned short* __restrict__ Htb,
                                                   const unsigned short* __restrict__ Udb,
                                                   unsigned short* __restrict__ Gb) {
    __shared__ __align__(16) short As[64 * LDT];
    __shared__ __align__(16) short Bs[64 * LDT];
    const int tid = threadIdx.x;
    const int wave = tid >> 6, lane = tid & 63;
    const int wm = wave >> 1, wn = wave & 1;
    const int quad = lane >> 4, lr = lane & 15, qk = quad * 8;
    const int n0 = blockIdx.x * 64, m0 = blockIdx.y * 64;
    const int arow = tid >> 2, aseg = tid & 3;
    floatx4 acc[2][2] = {};
    for (int k0 = 0; k0 < HIDDEN; k0 += 32) {
        *(float4*)(As + arow * LDT + aseg * 8) =
            *(const float4*)(Htb + (size_t)(m0 + arow) * HIDDEN + k0 + aseg * 8);
        *(float4*)(Bs + arow * LDT + aseg * 8) =
            *(const float4*)(Udb + (size_t)(n0 + arow) * HIDDEN + k0 + aseg * 8);
        __syncthreads();
        short8 a0 = *(const short8*)(As + (wm * 32 + lr) * LDT + qk);
        short8 a1 = *(const short8*)(As + (wm * 32 + 16 + lr) * LDT + qk);
        short8 b0 = *(const short8*)(Bs + (wn * 32 + lr) * LDT + qk);
        short8 b1 = *(const short8*)(Bs + (wn * 32 + 16 + lr) * LDT + qk);
        acc[0][0] = mfma16(a0, b0, acc[0][0]);
        acc[0][1] = mfma16(a0, b1, acc[0][1]);
        acc[1][0] = mfma16(a1, b0, acc[1][0]);
        acc[1][1] = mfma16(a1, b1, acc[1][1]);
        __syncthreads();
    }
#pragma unroll
    for (int mf = 0; mf < 2; ++mf)
#pragma unroll
        for (int nf = 0; nf < 2; ++nf)
#pragma unroll
            for (int r = 0; r < 4; ++r) {
                const int m = m0 + wm * 32 + mf * 16 + quad * 4 + r;
                const int n = n0 + wn * 32 + nf * 16 + lr;
                Gb[(size_t)m * HIDDEN + n] = f2bf(acc[mf][nf][r]);
            }
}

// ---------------------------------------------------------------------------
// init: yr_dot[b] = y_real[b,:24] . w[:24];  ctw = 0 (for fallback path)
// ---------------------------------------------------------------------------
__global__ void init_kernel(const float* __restrict__ y_real, const float* __restrict__ w,
                            float* __restrict__ yr_dot, float* __restrict__ ctw) {
    const int tid = blockIdx.x * blockDim.x + threadIdx.x;
    if (tid < BATCH) {
        float s = 0.f;
#pragma unroll
        for (int j = 0; j < WINDOW; ++j) s += y_real[tid * WINDOW + j] * w[j];
        yr_dot[tid] = s;
    }
    if (tid == 0) ctw[0] = 0.f;
}

// ===========================================================================
// FALLBACK PATH (round-4 proven kernels, 3 launches/step)
// ===========================================================================
__global__ __launch_bounds__(256) void s1_mfma(const unsigned short* __restrict__ db,
                                               const unsigned short* __restrict__ sb,
                                               const unsigned short* __restrict__ Wdb,
                                               const unsigned short* __restrict__ Gtb,
                                               const float* __restrict__ vd,
                                               float* __restrict__ lpart) {
    __shared__ __align__(16) short As[64 * LDT];
    __shared__ __align__(16) short Bs[32 * LDT];
    __shared__ float red[2][64];
    const int tid = threadIdx.x;
    const int wave = tid >> 6, lane = tid & 63;
    const int wm = wave >> 1, wn = wave & 1;
    const int quad = lane >> 4, lr = lane & 15, qk = quad * 8;
    const int m0 = (blockIdx.x & 31) * 64;
    const int nb = blockIdx.x >> 5;
    const int n0 = nb * 32;
    const int arow = tid >> 2, aseg = tid & 3;
    floatx4 acc[2] = {};
#pragma unroll
    for (int pass = 0; pass < 2; ++pass) {
        const unsigned short* A = pass ? sb : db;
        const unsigned short* B = Wdb + pass * HIDDEN;
        for (int k0 = 0; k0 < HIDDEN; k0 += 32) {
            *(float4*)(As + arow * LDT + aseg * 8) =
                *(const float4*)(A + (size_t)(m0 + arow) * HIDDEN + k0 + aseg * 8);
            if (tid < 128)
                *(float4*)(Bs + arow * LDT + aseg * 8) =
                    *(const float4*)(B + (size_t)(n0 + arow) * (2 * HIDDEN) + k0 + aseg * 8);
            __syncthreads();
            short8 a0 = *(const short8*)(As + (wm * 32 + lr) * LDT + qk);
            short8 a1 = *(const short8*)(As + (wm * 32 + 16 + lr) * LDT + qk);
            short8 b  = *(const short8*)(Bs + (wn * 16 + lr) * LDT + qk);
            acc[0] = mfma16(a0, b, acc[0]);
            acc[1] = mfma16(a1, b, acc[1]);
            __syncthreads();
        }
    }
#pragma unroll
    for (int mf = 0; mf < 2; ++mf) {
        float rs[4];
#pragma unroll
        for (int r = 0; r < 4; ++r) {
            const int b = m0 + wm * 32 + mf * 16 + quad * 4 + r;
            const int i = n0 + wn * 16 + lr;
            float v = tanhf(acc[mf][r] + bf2f(Gtb[(size_t)b * HIDDEN + i])) * vd[i];
            for (int msk = 1; msk < 16; msk <<= 1) v += __shfl_xor(v, msk, 16);
            rs[r] = v;
        }
        if (lr == 0)
#pragma unroll
            for (int r = 0; r < 4; ++r)
                red[wn][wm * 32 + mf * 16 + quad * 4 + r] = rs[r];
    }
    __syncthreads();
    if (tid < 64)
        lpart[(size_t)nb * BATCH + m0 + tid] = red[0][tid] + red[1][tid];
}

__global__ void mid_kernel(const float* __restrict__ lpart, const float* __restrict__ hw_t,
                           float* __restrict__ ctw, const float* __restrict__ b00,
                           float* __restrict__ yscal, const float* __restrict__ yr_dot,
                           float* __restrict__ y_out) {
    __shared__ float sm[1024];
    __shared__ float sm2[1024];
    __shared__ float ysh;
    const int tid = threadIdx.x;  // 1024
    float l0 = 0.f, l1 = 0.f;
#pragma unroll
    for (int p = 0; p < 16; ++p) {
        l0 += lpart[p * BATCH + tid];
        l1 += lpart[p * BATCH + tid + 1024];
    }
    sm[tid] = fmaxf(l0, l1);
    __syncthreads();
    for (int off = 512; off; off >>= 1) {
        if (tid < off) sm[tid] = fmaxf(sm[tid], sm[tid + off]);
        __syncthreads();
    }
    const float M = sm[0];
    __syncthreads();
    const float e0 = expf(l0 - M), e1 = expf(l1 - M);
    sm[tid]  = e0 + e1;
    sm2[tid] = e0 * hw_t[tid] + e1 * hw_t[1024 + tid];
    __syncthreads();
    for (int off = 512; off; off >>= 1) {
        if (tid < off) { sm[tid] += sm[tid + off]; sm2[tid] += sm2[tid + off]; }
        __syncthreads();
    }
    if (tid == 0) {
        const float c = ctw[0] + sm2[0] / sm[0];
        ctw[0] = c;
        ysh = c + b00[0];
        yscal[0] = ysh;
    }
    __syncthreads();
    if (y_out != nullptr) {
        const float ys = ysh;
        y_out[tid]        = yr_dot[tid] + ys;
        y_out[1024 + tid] = yr_dot[1024 + tid] + ys;
    }
}

__global__ __launch_bounds__(256) void gates_lstm_mfma(
        const unsigned short* __restrict__ db, const unsigned short* __restrict__ Whhb,
        const float* __restrict__ Wih, const float* __restrict__ bih,
        const float* __restrict__ bhh, const float* __restrict__ yr_dot,
        const float* __restrict__ yscal, const float* __restrict__ s_old,
        float* __restrict__ s_new, float* __restrict__ d_new,
        unsigned short* __restrict__ sb_new, unsigned short* __restrict__ db_new) {
    __shared__ __align__(16) short As[64 * LDT];
    __shared__ __align__(16) short Bs[4][32 * LDT];
    const int tid = threadIdx.x;
    const int wave = tid >> 6, lane = tid & 63;
    const int wm = wave >> 1, wn = wave & 1;
    const int quad = lane >> 4, lr = lane & 15, qk = quad * 8;
    const int m0 = (blockIdx.x & 31) * 64;
    const int n0 = (blockIdx.x >> 5) * 32;
    const int arow = tid >> 2, aseg = tid & 3;
    floatx4 acc[4][2] = {};
    for (int k0 = 0; k0 < HIDDEN; k0 += 32) {
        *(float4*)(As + arow * LDT + aseg * 8) =
            *(const float4*)(db + (size_t)(m0 + arow) * HIDDEN + k0 + aseg * 8);
#pragma unroll
        for (int j = 0; j < 2; ++j) {
            const int c = tid + 256 * j;
            const int g = c >> 7, cc = c & 127, row = cc >> 2, seg = cc & 3;
            *(float4*)(Bs[g] + row * LDT + seg * 8) =
                *(const float4*)(Whhb + (size_t)(g * HIDDEN + n0 + row) * HIDDEN + k0 + seg * 8);
        }
        __syncthreads();
        short8 a0 = *(const short8*)(As + (wm * 32 + lr) * LDT + qk);
        short8 a1 = *(const short8*)(As + (wm * 32 + 16 + lr) * LDT + qk);
#pragma unroll
        for (int g = 0; g < 4; ++g) {
            short8 b = *(const short8*)(Bs[g] + (wn * 16 + lr) * LDT + qk);
            acc[g][0] = mfma16(a0, b, acc[g][0]);
            acc[g][1] = mfma16(a1, b, acc[g][1]);
        }
        __syncthreads();
    }
    const float ys = yscal[0];
    const int i = n0 + wn * 16 + lr;
    float wi[4], cb[4];
#pragma unroll
    for (int g = 0; g < 4; ++g) {
        wi[g] = Wih[g * HIDDEN + i];
        cb[g] = bih[g * HIDDEN + i] + bhh[g * HIDDEN + i];
    }
#pragma unroll
    for (int mf = 0; mf < 2; ++mf) {
#pragma unroll
        for (int r = 0; r < 4; ++r) {
            const int b = m0 + wm * 32 + mf * 16 + quad * 4 + r;
            const float yf = yr_dot[b] + ys;
            const size_t idx = (size_t)b * HIDDEN + i;
            const float ig = acc[0][mf][r] + yf * wi[0] + cb[0];
            const float fg = acc[1][mf][r] + yf * wi[1] + cb[1];
            const float gg = acc[2][mf][r] + yf * wi[2] + cb[2];
            const float og = acc[3][mf][r] + yf * wi[3] + cb[3];
            const float sn = sigmoidf(fg) * s_old[idx] + sigmoidf(ig) * tanhf(gg);
            const float dn = sigmoidf(og) * tanhf(sn);
            s_new[idx] = sn;
            sb_new[idx] = f2bf(sn);
            db_new[idx] = f2bf(dn);
            if (d_new != nullptr) d_new[idx] = dn;
        }
    }
}

// ===========================================================================
// COOPERATIVE PATH: persistent scan, 256 blocks (1/CU — co-residency trivial)
// Block bx: m-tile = bx&31 (64 rows), n-tile = bx>>5 (64 cols).
// ===========================================================================
__global__ __launch_bounds__(256) void scan_coop(
        const unsigned short* __restrict__ dbb0, unsigned short* __restrict__ dbb1,
        const unsigned short* __restrict__ sbb0, unsigned short* __restrict__ sbb1,
        float* __restrict__ sbuf0, float* __restrict__ sbuf1,
        const float* __restrict__ s_init,
        const unsigned short* __restrict__ Wdb, const unsigned short* __restrict__ Whhb,
        const unsigned short* __restrict__ Gb, const float* __restrict__ vd,
        const float* __restrict__ Wih, const float* __restrict__ bih,
        const float* __restrict__ bhh, const float* __restrict__ yr_dot,
        const float* __restrict__ hw, const float* __restrict__ b00,
        float* __restrict__ lpart, float* __restrict__ y_out,
        float* __restrict__ d_out_f, float* __restrict__ s_out_f) {
    __shared__ __align__(16) short As[64 * LDT];
    __shared__ __align__(16) short Bwd[64 * LDT];
    __shared__ __align__(16) short Bwh[4][64 * LDT];
    __shared__ float red[2][64];
    __shared__ float smax[256], ssum[256], ssum2[256];

    cg::grid_group gridg = cg::this_grid();

    const int tid = threadIdx.x;
    const int wave = tid >> 6, lane = tid & 63;
    const int wm = wave >> 1, wn = wave & 1;
    const int quad = lane >> 4, lr = lane & 15, qk = quad * 8;
    const int bx = blockIdx.x;
    const int m0 = (bx & 31) * 64;
    const int nt = bx >> 5;              // 0..7
    const int n0 = nt * 64;
    const int arow = tid >> 2, aseg = tid & 3;

    const float b00v = b00[0];
    int icolv[2];
    float vdv[2], wi[4][2], cbv[4][2];
#pragma unroll
    for (int nf = 0; nf < 2; ++nf) {
        icolv[nf] = n0 + wn * 32 + nf * 16 + lr;
        vdv[nf] = vd[icolv[nf]];
#pragma unroll
        for (int g = 0; g < 4; ++g) {
            wi[g][nf]  = Wih[g * HIDDEN + icolv[nf]];
            cbv[g][nf] = bih[g * HIDDEN + icolv[nf]] + bhh[g * HIDDEN + icolv[nf]];
        }
    }
    float yrc[2][4];
#pragma unroll
    for (int mf = 0; mf < 2; ++mf)
#pragma unroll
        for (int r = 0; r < 4; ++r)
            yrc[mf][r] = yr_dot[m0 + wm * 32 + mf * 16 + quad * 4 + r];

    float ctw = 0.f;   // identical in every block (deterministic redundant compute)

    for (int t = 0; t < WINDOW; ++t) {
        const int rp = t & 1;
        const unsigned short* dcur = rp ? dbb1 : dbb0;
        const unsigned short* scur = rp ? sbb1 : sbb0;
        unsigned short* dnxt = rp ? (unsigned short*)dbb0 : dbb1;
        unsigned short* snxt = rp ? (unsigned short*)sbb0 : sbb1;
        const float* s_old = (t == 0) ? s_init : (rp ? sbuf0 : sbuf1);
        float* s_new = (t == WINDOW - 1) ? s_out_f : (rp ? sbuf1 : sbuf0);
        const unsigned short* Gtb = Gb + (size_t)t * BH;

        // ---------- Phase A: fused s1 (K=1024) + gates (K=512) GEMMs ----------
        floatx4 acc1[2][2] = {};
        floatx4 accg[4][2][2] = {};
        for (int k0 = 0; k0 < HIDDEN; k0 += 32) {
            *(float4*)(As + arow * LDT + aseg * 8) =
                *(const float4*)(dcur + (size_t)(m0 + arow) * HIDDEN + k0 + aseg * 8);
            *(float4*)(Bwd + arow * LDT + aseg * 8) =
                *(const float4*)(Wdb + (size_t)(n0 + arow) * (2 * HIDDEN) + k0 + aseg * 8);
#pragma unroll
            for (int j = 0; j < 4; ++j) {
                const int c = tid + 256 * j;          // 1024 chunks: 4g x 64row x 4seg
                const int g = c >> 8, cc = c & 255, row = cc >> 2, seg = cc & 3;
                *(float4*)(Bwh[g] + row * LDT + seg * 8) =
                    *(const float4*)(Whhb + (size_t)(g * HIDDEN + n0 + row) * HIDDEN + k0 + seg * 8);
            }
            __syncthreads();
            short8 a0  = *(const short8*)(As + (wm * 32 + lr) * LDT + qk);
            short8 a1  = *(const short8*)(As + (wm * 32 + 16 + lr) * LDT + qk);
            short8 bw0 = *(const short8*)(Bwd + (wn * 32 + lr) * LDT + qk);
            short8 bw1 = *(const short8*)(Bwd + (wn * 32 + 16 + lr) * LDT + qk);
            acc1[0][0] = mfma16(a0, bw0, acc1[0][0]);
            acc1[0][1] = mfma16(a0, bw1, acc1[0][1]);
            acc1[1][0] = mfma16(a1, bw0, acc1[1][0]);
            acc1[1][1] = mfma16(a1, bw1, acc1[1][1]);
#pragma unroll
            for (int g = 0; g < 4; ++g) {
                short8 bh0 = *(const short8*)(Bwh[g] + (wn * 32 + lr) * LDT + qk);
                short8 bh1 = *(const short8*)(Bwh[g] + (wn * 32 + 16 + lr) * LDT + qk);
                accg[g][0][0] = mfma16(a0, bh0, accg[g][0][0]);
                accg[g][0][1] = mfma16(a0, bh1, accg[g][0][1]);
                accg[g][1][0] = mfma16(a1, bh0, accg[g][1][0]);
                accg[g][1][1] = mfma16(a1, bh1, accg[g][1][1]);
            }
            __syncthreads();
        }
        // pass 1: A = s0, Wd cols [512,1024) (s1 only)
        for (int k0 = 0; k0 < HIDDEN; k0 += 32) {
            *(float4*)(As + arow * LDT + aseg * 8) =
                *(const float4*)(scur + (size_t)(m0 + arow) * HIDDEN + k0 + aseg * 8);
            *(float4*)(Bwd + arow * LDT + aseg * 8) =
                *(const float4*)(Wdb + (size_t)(n0 + arow) * (2 * HIDDEN) + HIDDEN + k0 + aseg * 8);
            __syncthreads();
            short8 a0  = *(const short8*)(As + (wm * 32 + lr) * LDT + qk);
            short8 a1  = *(const short8*)(As + (wm * 32 + 16 + lr) * LDT + qk);
            short8 bw0 = *(const short8*)(Bwd + (wn * 32 + lr) * LDT + qk);
            short8 bw1 = *(const short8*)(Bwd + (wn * 32 + 16 + lr) * LDT + qk);
            acc1[0][0] = mfma16(a0, bw0, acc1[0][0]);
            acc1[0][1] = mfma16(a0, bw1, acc1[0][1]);
            acc1[1][0] = mfma16(a1, bw0, acc1[1][0]);
            acc1[1][1] = mfma16(a1, bw1, acc1[1][1]);
            __syncthreads();
        }
        // s1 epilogue: tanh(.+Gt)*vd, reduce over this block's 64 cols
#pragma unroll
        for (int mf = 0; mf < 2; ++mf) {
            float rs[4];
#pragma unroll
            for (int r = 0; r < 4; ++r) {
                const int b = m0 + wm * 32 + mf * 16 + quad * 4 + r;
                float v = 0.f;
#pragma unroll
                for (int nf = 0; nf < 2; ++nf)
                    v += tanhf(acc1[mf][nf][r] + bf2f(Gtb[(size_t)b * HIDDEN + icolv[nf]])) * vdv[nf];
                for (int msk = 1; msk < 16; msk <<= 1) v += __shfl_xor(v, msk, 16);
                rs[r] = v;
            }
            if (lr == 0)
#pragma unroll
                for (int r = 0; r < 4; ++r)
                    red[wn][wm * 32 + mf * 16 + quad * 4 + r] = rs[r];
        }
        __syncthreads();
        if (tid < 64)
            lpart[(size_t)nt * BATCH + m0 + tid] = red[0][tid] + red[1][tid];

        gridg.sync();

        // ---------- Phase B: redundant softmax + ctw recursion ----------
        const int bb = tid * 8;
        float l[8] = {0.f, 0.f, 0.f, 0.f, 0.f, 0.f, 0.f, 0.f};
#pragma unroll
        for (int p = 0; p < 8; ++p) {
            const float4 u0 = *(const float4*)(lpart + (size_t)p * BATCH + bb);
            const float4 u1 = *(const float4*)(lpart + (size_t)p * BATCH + bb + 4);
            l[0] += u0.x; l[1] += u0.y; l[2] += u0.z; l[3] += u0.w;
            l[4] += u1.x; l[5] += u1.y; l[6] += u1.z; l[7] += u1.w;
        }
        float mx = l[0];
#pragma unroll
        for (int j = 1; j < 8; ++j) mx = fmaxf(mx, l[j]);
        smax[tid] = mx;
        __syncthreads();
        for (int o = 128; o; o >>= 1) {
            if (tid < o) smax[tid] = fmaxf(smax[tid], smax[tid + o]);
            __syncthreads();
        }
        const float M = smax[0];
        const float* hwt = hw + (size_t)t * BATCH;
        const float4 h0 = *(const float4*)(hwt + bb);
        const float4 h1 = *(const float4*)(hwt + bb + 4);
        const float hv[8] = {h0.x, h0.y, h0.z, h0.w, h1.x, h1.y, h1.z, h1.w};
        float se = 0.f, sh = 0.f;
#pragma unroll
        for (int j = 0; j < 8; ++j) {
            const float e = expf(l[j] - M);
            se += e;
            sh += e * hv[j];
        }
        ssum[tid] = se; ssum2[tid] = sh;
        __syncthreads();
        for (int o = 128; o; o >>= 1) {
            if (tid < o) { ssum[tid] += ssum[tid + o]; ssum2[tid] += ssum2[tid + o]; }
            __syncthreads();
        }
        ctw += ssum2[0] / ssum[0];
        const float ys = ctw + b00v;

        // ---------- Phase C: gates epilogue + LSTM update ----------
#pragma unroll
        for (int nf = 0; nf < 2; ++nf) {
#pragma unroll
            for (int mf = 0; mf < 2; ++mf) {
#pragma unroll
                for (int r = 0; r < 4; ++r) {
                    const int b = m0 + wm * 32 + mf * 16 + quad * 4 + r;
                    const float yf = yrc[mf][r] + ys;
                    const size_t idx = (size_t)b * HIDDEN + icolv[nf];
                    const float ig = accg[0][mf][nf][r] + yf * wi[0][nf] + cbv[0][nf];
                    const float fg = accg[1][mf][nf][r] + yf * wi[1][nf] + cbv[1][nf];
                    const float gg = accg[2][mf][nf][r] + yf * wi[2][nf] + cbv[2][nf];
                    const float og = accg[3][mf][nf][r] + yf * wi[3][nf] + cbv[3][nf];
                    const float sn = sigmoidf(fg) * s_old[idx] + sigmoidf(ig) * tanhf(gg);
                    const float dn = sigmoidf(og) * tanhf(sn);
                    s_new[idx] = sn;
                    snxt[idx] = f2bf(sn);
                    dnxt[idx] = f2bf(dn);
                    if (t == WINDOW - 1) d_out_f[idx] = dn;
                }
            }
        }
        if (t == WINDOW - 1 && nt == 0 && tid < 64)
            y_out[m0 + tid] = yr_dot[m0 + tid] + ys;

        gridg.sync();
    }
}

// ---------------------------------------------------------------------------
extern "C" void kernel_launch(void* const* d_in, const int* in_sizes, int n_in,
                              void* d_out, int out_size, void* d_ws, size_t ws_size,
                              hipStream_t stream) {
    const float* Z      = (const float*)d_in[0];
    const float* d_init = (const float*)d_in[1];
    const float* s_init = (const float*)d_in[2];
    const float* y_real = (const float*)d_in[3];
    const float* vd     = (const float*)d_in[4];
    const float* Wd     = (const float*)d_in[5];
    const float* Ud     = (const float*)d_in[6];
    const float* w      = (const float*)d_in[7];
    const float* b00    = (const float*)d_in[8];
    const float* conv_w = (const float*)d_in[9];
    const float* conv_b = (const float*)d_in[10];
    const float* Wih    = (const float*)d_in[11];
    const float* Whh    = (const float*)d_in[12];
    const float* bih    = (const float*)d_in[13];
    const float* bhh    = (const float*)d_in[14];

    float* ws = (float*)d_ws;
    size_t off = 0;
    unsigned short* Htb = (unsigned short*)(ws + off);  off += (size_t)WINDOW * BH / 2;
    unsigned short* Gb  = (unsigned short*)(ws + off);  off += (size_t)WINDOW * BH / 2;
    unsigned short* dbb0 = (unsigned short*)(ws + off);  off += BH / 2;
    unsigned short* dbb1 = (unsigned short*)(ws + off);  off += BH / 2;
    unsigned short* sbb0 = (unsigned short*)(ws + off);  off += BH / 2;
    unsigned short* sbb1 = (unsigned short*)(ws + off);  off += BH / 2;
    float* sbuf0 = ws + off;  off += BH;
    float* sbuf1 = ws + off;  off += BH;
    unsigned short* Wdb  = (unsigned short*)(ws + off);  off += (size_t)HIDDEN * 2 * HIDDEN / 2;
    unsigned short* Udb  = (unsigned short*)(ws + off);  off += (size_t)HIDDEN * HIDDEN / 2;
    unsigned short* Whhb = (unsigned short*)(ws + off);  off += (size_t)H4 * HIDDEN / 2;
    float* hw     = ws + off;  off += (size_t)WINDOW * BATCH;
    float* lpart  = ws + off;  off += (size_t)16 * BATCH;
    float* yr_dot = ws + off;  off += BATCH;
    float* ctw    = ws + off;  off += 4;
    float* yscal  = ws + off;  off += 4;

    float* out = (float*)d_out;
    float* y_out   = out;
    float* d_out_f = out + BATCH;
    float* s_out_f = out + BATCH + (size_t)BH;

    // --- one-time prep ---
    cvt5_kernel<<<3840, 256, 0, stream>>>(Wd, Wdb, Ud, Udb, Whh, Whhb,
                                          d_init, dbb0, s_init, sbb0);
    conv_kernel<<<BATCH, 256, 0, stream>>>(Z, conv_w, conv_b, (unsigned int*)Htb);
    hw_kernel<<<(WINDOW * BATCH) / 4, 256, 0, stream>>>(Htb, w, hw);
    {
        dim3 grid(HIDDEN / 64, (WINDOW * BATCH) / 64);
        g_gemm_mfma<<<grid, 256, 0, stream>>>(Htb, Udb, Gb);
    }
    init_kernel<<<8, 256, 0, stream>>>(y_real, w, yr_dot, ctw);

    // --- cooperative persistent scan (256 blocks = 1/CU, co-residency trivial) ---
    const unsigned short* dbb0c = dbb0;
    const unsigned short* sbb0c = sbb0;
    void* args[] = {
        (void*)&dbb0c, (void*)&dbb1, (void*)&sbb0c, (void*)&sbb1,
        (void*)&sbuf0, (void*)&sbuf1, (void*)&s_init,
        (void*)&Wdb, (void*)&Whhb, (void*)&Gb, (void*)&vd,
        (void*)&Wih, (void*)&bih, (void*)&bhh, (void*)&yr_dot,
        (void*)&hw, (void*)&b00, (void*)&lpart, (void*)&y_out,
        (void*)&d_out_f, (void*)&s_out_f,
    };
    hipError_t cerr = hipLaunchCooperativeKernel((void*)scan_coop, dim3(256), dim3(256),
                                                 args, 0, stream);
    if (cerr != hipSuccess) {
        (void)hipGetLastError();   // clear sticky error state
        // --- fallback: proven round-4 3-launch scan ---
        const float* s_read = s_init;
        int pp = 0;
        for (int t = 0; t < WINDOW; ++t) {
            const unsigned short* Gtb = Gb + (size_t)t * BH;
            unsigned short* dbbs[2] = {dbb0, dbb1};
            unsigned short* sbbs[2] = {sbb0, sbb1};
            float* sbufs[2] = {sbuf0, sbuf1};
            s1_mfma<<<512, 256, 0, stream>>>(dbbs[pp], sbbs[pp], Wdb, Gtb, vd, lpart);
            mid_kernel<<<1, 1024, 0, stream>>>(lpart, hw + t * BATCH, ctw, b00, yscal,
                                               yr_dot, (t == WINDOW - 1) ? y_out : nullptr);
            float* s_w = (t == WINDOW - 1) ? s_out_f : sbufs[t & 1];
            float* d_w = (t == WINDOW - 1) ? d_out_f : nullptr;
            gates_lstm_mfma<<<512, 256, 0, stream>>>(dbbs[pp], Whhb, Wih, bih, bhh,
                                                     yr_dot, yscal, s_read, s_w, d_w,
                                                     sbbs[1 - pp], dbbs[1 - pp]);
            s_read = s_w;
            pp ^= 1;
        }
    }
}

// Round 7
// 2648.510 us; speedup vs baseline: 1.0220x; 1.0220x over previous
//
#include <hip/hip_runtime.h>
#include <math.h>

#define HIDDEN 512
#define WINDOW 24
#define KSZ 3
#define BATCH 2048
#define L_IN 514
#define H4 2048
#define LDT 40                    // padded LDS row stride (shorts) for 32-k tiles
#define BH (BATCH * HIDDEN)
#define GRIDB 256                 // persistent grid size (1 block/CU)

typedef short short8 __attribute__((ext_vector_type(8)));
typedef float floatx4 __attribute__((ext_vector_type(4)));

__device__ __forceinline__ floatx4 mfma16(short8 a, short8 b, floatx4 c) {
    return __builtin_amdgcn_mfma_f32_16x16x32_bf16(a, b, c, 0, 0, 0);
}
__device__ __forceinline__ unsigned short f2bf(float x) {
    union { float f; unsigned u; } v; v.f = x;
    unsigned r = v.u + 0x7fff + ((v.u >> 16) & 1);   // RTNE
    return (unsigned short)(r >> 16);
}
__device__ __forceinline__ float bf2f(unsigned short u) {
    union { unsigned u; float f; } v; v.u = ((unsigned)u) << 16;
    return v.f;
}
__device__ __forceinline__ float sigmoidf(float x) { return 1.f / (1.f + expf(-x)); }

// ---------------------------------------------------------------------------
// Fast sense-reversing grid barrier (device-scope). ~2-5 us vs ~50 us for
// cg::grid_group::sync(). Requires all GRIDB blocks co-resident (coop launch).
// ---------------------------------------------------------------------------
__device__ __forceinline__ void grid_barrier(unsigned* cnt, unsigned* gen, unsigned& lgen) {
    __syncthreads();
    if (threadIdx.x == 0) {
        __threadfence();                                     // release prior writes
        const unsigned g = lgen;
        if (atomicAdd(cnt, 1u) == GRIDB - 1u) {
            __hip_atomic_store(cnt, 0u, __ATOMIC_RELAXED, __HIP_MEMORY_SCOPE_AGENT);
            __hip_atomic_store(gen, g + 1u, __ATOMIC_RELEASE, __HIP_MEMORY_SCOPE_AGENT);
        } else {
            while (__hip_atomic_load(gen, __ATOMIC_ACQUIRE, __HIP_MEMORY_SCOPE_AGENT) <= g)
                __builtin_amdgcn_s_sleep(1);
        }
        __threadfence();                                     // acquire: drop stale cache
        lgen = g + 1u;
    }
    __syncthreads();
}

// ---------------------------------------------------------------------------
// cvt5: fp32 -> bf16 for Wd, Ud, Whh, d_init, s_init
// ---------------------------------------------------------------------------
__global__ void cvt5_kernel(const float* __restrict__ s0, unsigned short* __restrict__ d0,
                            const float* __restrict__ s1, unsigned short* __restrict__ d1,
                            const float* __restrict__ s2, unsigned short* __restrict__ d2,
                            const float* __restrict__ s3, unsigned short* __restrict__ d3,
                            const float* __restrict__ s4, unsigned short* __restrict__ d4) {
    const int g = blockIdx.x * blockDim.x + threadIdx.x;   // one float4 per thread
    const float* src; unsigned short* dst; int off;
    if      (g < 131072) { src = s0; dst = d0; off = g; }
    else if (g < 196608) { src = s1; dst = d1; off = g - 131072; }
    else if (g < 458752) { src = s2; dst = d2; off = g - 196608; }
    else if (g < 720896) { src = s3; dst = d3; off = g - 458752; }
    else if (g < 983040) { src = s4; dst = d4; off = g - 720896; }
    else return;
    float4 v = ((const float4*)src)[off];
    uint2 u;
    u.x = (unsigned)f2bf(v.x) | ((unsigned)f2bf(v.y) << 16);
    u.y = (unsigned)f2bf(v.z) | ((unsigned)f2bf(v.w) << 16);
    ((uint2*)dst)[off] = u;
}

// ---------------------------------------------------------------------------
// conv1d(2->24, k=3, valid) + bias + relu -> Htb bf16 [t][b][i]
// ---------------------------------------------------------------------------
__global__ void conv_kernel(const float* __restrict__ Z, const float* __restrict__ conv_w,
                            const float* __restrict__ conv_b,
                            unsigned int* __restrict__ Htu) {
    __shared__ float cw[WINDOW * 6];
    __shared__ float cb[WINDOW];
    const int b = blockIdx.x;
    if (threadIdx.x < WINDOW * 6) cw[threadIdx.x] = conv_w[threadIdx.x];
    if (threadIdx.x < WINDOW) cb[threadIdx.x] = conv_b[threadIdx.x];
    __syncthreads();
    const float* z0 = Z + (size_t)b * L_IN;
    const float* z1 = z0 + (size_t)BATCH * L_IN;
    const int i0 = threadIdx.x * 2;
    const float a0 = z0[i0], a1 = z0[i0 + 1], a2 = z0[i0 + 2], a3 = z0[i0 + 3];
    const float c0 = z1[i0], c1 = z1[i0 + 1], c2 = z1[i0 + 2], c3 = z1[i0 + 3];
#pragma unroll
    for (int o = 0; o < WINDOW; ++o) {
        const float* wc = cw + o * 6;
        float v0 = fmaxf(cb[o] + a0 * wc[0] + a1 * wc[1] + a2 * wc[2]
                               + c0 * wc[3] + c1 * wc[4] + c2 * wc[5], 0.f);
        float v1 = fmaxf(cb[o] + a1 * wc[0] + a2 * wc[1] + a3 * wc[2]
                               + c1 * wc[3] + c2 * wc[4] + c3 * wc[5], 0.f);
        Htu[((size_t)o * BATCH + b) * 256 + threadIdx.x] =
            (unsigned)f2bf(v0) | ((unsigned)f2bf(v1) << 16);
    }
}

// ---------------------------------------------------------------------------
// hw[t][b] = H_t[b,:] . w[24:]
// ---------------------------------------------------------------------------
__global__ void hw_kernel(const unsigned short* __restrict__ Htb,
                          const float* __restrict__ w, float* __restrict__ hw) {
    const int row = blockIdx.x * 4 + (threadIdx.x >> 6);
    const int lane = threadIdx.x & 63;
    short8 v = *(const short8*)(Htb + (size_t)row * HIDDEN + lane * 8);
    float acc = 0.f;
#pragma unroll
    for (int j = 0; j < 8; ++j)
        acc += bf2f((unsigned short)v[j]) * w[WINDOW + lane * 8 + j];
    for (int m = 32; m; m >>= 1) acc += __shfl_xor(acc, m, 64);
    if (lane == 0) hw[row] = acc;
}

// ---------------------------------------------------------------------------
// Gb = Htb[49152 x 512] @ Udb^T  (bf16 out)
// ---------------------------------------------------------------------------
__global__ __launch_bounds__(256) void g_gemm_mfma(const unsigned short* __restrict__ Htb,
                                                   const unsigned short* __restrict__ Udb,
                                                   unsigned short* __restrict__ Gb) {
    __shared__ __align__(16) short As[64 * LDT];
    __shared__ __align__(16) short Bs[64 * LDT];
    const int tid = threadIdx.x;
    const int wave = tid >> 6, lane = tid & 63;
    const int wm = wave >> 1, wn = wave & 1;
    const int quad = lane >> 4, lr = lane & 15, qk = quad * 8;
    const int n0 = blockIdx.x * 64, m0 = blockIdx.y * 64;
    const int arow = tid >> 2, aseg = tid & 3;
    floatx4 acc[2][2] = {};
    for (int k0 = 0; k0 < HIDDEN; k0 += 32) {
        *(float4*)(As + arow * LDT + aseg * 8) =
            *(const float4*)(Htb + (size_t)(m0 + arow) * HIDDEN + k0 + aseg * 8);
        *(float4*)(Bs + arow * LDT + aseg * 8) =
            *(const float4*)(Udb + (size_t)(n0 + arow) * HIDDEN + k0 + aseg * 8);
        __syncthreads();
        short8 a0 = *(const short8*)(As + (wm * 32 + lr) * LDT + qk);
        short8 a1 = *(const short8*)(As + (wm * 32 + 16 + lr) * LDT + qk);
        short8 b0 = *(const short8*)(Bs + (wn * 32 + lr) * LDT + qk);
        short8 b1 = *(const short8*)(Bs + (wn * 32 + 16 + lr) * LDT + qk);
        acc[0][0] = mfma16(a0, b0, acc[0][0]);
        acc[0][1] = mfma16(a0, b1, acc[0][1]);
        acc[1][0] = mfma16(a1, b0, acc[1][0]);
        acc[1][1] = mfma16(a1, b1, acc[1][1]);
        __syncthreads();
    }
#pragma unroll
    for (int mf = 0; mf < 2; ++mf)
#pragma unroll
        for (int nf = 0; nf < 2; ++nf)
#pragma unroll
            for (int r = 0; r < 4; ++r) {
                const int m = m0 + wm * 32 + mf * 16 + quad * 4 + r;
                const int n = n0 + wn * 32 + nf * 16 + lr;
                Gb[(size_t)m * HIDDEN + n] = f2bf(acc[mf][nf][r]);
            }
}

// ---------------------------------------------------------------------------
// init: yr_dot; zero ctw (fallback) and barrier state (coop)
// ---------------------------------------------------------------------------
__global__ void init_kernel(const float* __restrict__ y_real, const float* __restrict__ w,
                            float* __restrict__ yr_dot, float* __restrict__ ctw,
                            unsigned* __restrict__ bar) {
    const int tid = blockIdx.x * blockDim.x + threadIdx.x;
    if (tid < BATCH) {
        float s = 0.f;
#pragma unroll
        for (int j = 0; j < WINDOW; ++j) s += y_real[tid * WINDOW + j] * w[j];
        yr_dot[tid] = s;
    }
    if (tid == 0) ctw[0] = 0.f;
    if (tid < 8) bar[tid] = 0u;
}

// ===========================================================================
// FALLBACK PATH (round-4 proven kernels, 3 launches/step)
// ===========================================================================
__global__ __launch_bounds__(256) void s1_mfma(const unsigned short* __restrict__ db,
                                               const unsigned short* __restrict__ sb,
                                               const unsigned short* __restrict__ Wdb,
                                               const unsigned short* __restrict__ Gtb,
                                               const float* __restrict__ vd,
                                               float* __restrict__ lpart) {
    __shared__ __align__(16) short As[64 * LDT];
    __shared__ __align__(16) short Bs[32 * LDT];
    __shared__ float red[2][64];
    const int tid = threadIdx.x;
    const int wave = tid >> 6, lane = tid & 63;
    const int wm = wave >> 1, wn = wave & 1;
    const int quad = lane >> 4, lr = lane & 15, qk = quad * 8;
    const int m0 = (blockIdx.x & 31) * 64;
    const int nb = blockIdx.x >> 5;
    const int n0 = nb * 32;
    const int arow = tid >> 2, aseg = tid & 3;
    floatx4 acc[2] = {};
#pragma unroll
    for (int pass = 0; pass < 2; ++pass) {
        const unsigned short* A = pass ? sb : db;
        const unsigned short* B = Wdb + pass * HIDDEN;
        for (int k0 = 0; k0 < HIDDEN; k0 += 32) {
            *(float4*)(As + arow * LDT + aseg * 8) =
                *(const float4*)(A + (size_t)(m0 + arow) * HIDDEN + k0 + aseg * 8);
            if (tid < 128)
                *(float4*)(Bs + arow * LDT + aseg * 8) =
                    *(const float4*)(B + (size_t)(n0 + arow) * (2 * HIDDEN) + k0 + aseg * 8);
            __syncthreads();
            short8 a0 = *(const short8*)(As + (wm * 32 + lr) * LDT + qk);
            short8 a1 = *(const short8*)(As + (wm * 32 + 16 + lr) * LDT + qk);
            short8 b  = *(const short8*)(Bs + (wn * 16 + lr) * LDT + qk);
            acc[0] = mfma16(a0, b, acc[0]);
            acc[1] = mfma16(a1, b, acc[1]);
            __syncthreads();
        }
    }
#pragma unroll
    for (int mf = 0; mf < 2; ++mf) {
        float rs[4];
#pragma unroll
        for (int r = 0; r < 4; ++r) {
            const int b = m0 + wm * 32 + mf * 16 + quad * 4 + r;
            const int i = n0 + wn * 16 + lr;
            float v = tanhf(acc[mf][r] + bf2f(Gtb[(size_t)b * HIDDEN + i])) * vd[i];
            for (int msk = 1; msk < 16; msk <<= 1) v += __shfl_xor(v, msk, 16);
            rs[r] = v;
        }
        if (lr == 0)
#pragma unroll
            for (int r = 0; r < 4; ++r)
                red[wn][wm * 32 + mf * 16 + quad * 4 + r] = rs[r];
    }
    __syncthreads();
    if (tid < 64)
        lpart[(size_t)nb * BATCH + m0 + tid] = red[0][tid] + red[1][tid];
}

__global__ void mid_kernel(const float* __restrict__ lpart, const float* __restrict__ hw_t,
                           float* __restrict__ ctw, const float* __restrict__ b00,
                           float* __restrict__ yscal, const float* __restrict__ yr_dot,
                           float* __restrict__ y_out) {
    __shared__ float sm[1024];
    __shared__ float sm2[1024];
    __shared__ float ysh;
    const int tid = threadIdx.x;  // 1024
    float l0 = 0.f, l1 = 0.f;
#pragma unroll
    for (int p = 0; p < 16; ++p) {
        l0 += lpart[p * BATCH + tid];
        l1 += lpart[p * BATCH + tid + 1024];
    }
    sm[tid] = fmaxf(l0, l1);
    __syncthreads();
    for (int off = 512; off; off >>= 1) {
        if (tid < off) sm[tid] = fmaxf(sm[tid], sm[tid + off]);
        __syncthreads();
    }
    const float M = sm[0];
    __syncthreads();
    const float e0 = expf(l0 - M), e1 = expf(l1 - M);
    sm[tid]  = e0 + e1;
    sm2[tid] = e0 * hw_t[tid] + e1 * hw_t[1024 + tid];
    __syncthreads();
    for (int off = 512; off; off >>= 1) {
        if (tid < off) { sm[tid] += sm[tid + off]; sm2[tid] += sm2[tid + off]; }
        __syncthreads();
    }
    if (tid == 0) {
        const float c = ctw[0] + sm2[0] / sm[0];
        ctw[0] = c;
        ysh = c + b00[0];
        yscal[0] = ysh;
    }
    __syncthreads();
    if (y_out != nullptr) {
        const float ys = ysh;
        y_out[tid]        = yr_dot[tid] + ys;
        y_out[1024 + tid] = yr_dot[1024 + tid] + ys;
    }
}

__global__ __launch_bounds__(256) void gates_lstm_mfma(
        const unsigned short* __restrict__ db, const unsigned short* __restrict__ Whhb,
        const float* __restrict__ Wih, const float* __restrict__ bih,
        const float* __restrict__ bhh, const float* __restrict__ yr_dot,
        const float* __restrict__ yscal, const float* __restrict__ s_old,
        float* __restrict__ s_new, float* __restrict__ d_new,
        unsigned short* __restrict__ sb_new, unsigned short* __restrict__ db_new) {
    __shared__ __align__(16) short As[64 * LDT];
    __shared__ __align__(16) short Bs[4][32 * LDT];
    const int tid = threadIdx.x;
    const int wave = tid >> 6, lane = tid & 63;
    const int wm = wave >> 1, wn = wave & 1;
    const int quad = lane >> 4, lr = lane & 15, qk = quad * 8;
    const int m0 = (blockIdx.x & 31) * 64;
    const int n0 = (blockIdx.x >> 5) * 32;
    const int arow = tid >> 2, aseg = tid & 3;
    floatx4 acc[4][2] = {};
    for (int k0 = 0; k0 < HIDDEN; k0 += 32) {
        *(float4*)(As + arow * LDT + aseg * 8) =
            *(const float4*)(db + (size_t)(m0 + arow) * HIDDEN + k0 + aseg * 8);
#pragma unroll
        for (int j = 0; j < 2; ++j) {
            const int c = tid + 256 * j;
            const int g = c >> 7, cc = c & 127, row = cc >> 2, seg = cc & 3;
            *(float4*)(Bs[g] + row * LDT + seg * 8) =
                *(const float4*)(Whhb + (size_t)(g * HIDDEN + n0 + row) * HIDDEN + k0 + seg * 8);
        }
        __syncthreads();
        short8 a0 = *(const short8*)(As + (wm * 32 + lr) * LDT + qk);
        short8 a1 = *(const short8*)(As + (wm * 32 + 16 + lr) * LDT + qk);
#pragma unroll
        for (int g = 0; g < 4; ++g) {
            short8 b = *(const short8*)(Bs[g] + (wn * 16 + lr) * LDT + qk);
            acc[g][0] = mfma16(a0, b, acc[g][0]);
            acc[g][1] = mfma16(a1, b, acc[g][1]);
        }
        __syncthreads();
    }
    const float ys = yscal[0];
    const int i = n0 + wn * 16 + lr;
    float wi[4], cb[4];
#pragma unroll
    for (int g = 0; g < 4; ++g) {
        wi[g] = Wih[g * HIDDEN + i];
        cb[g] = bih[g * HIDDEN + i] + bhh[g * HIDDEN + i];
    }
#pragma unroll
    for (int mf = 0; mf < 2; ++mf) {
#pragma unroll
        for (int r = 0; r < 4; ++r) {
            const int b = m0 + wm * 32 + mf * 16 + quad * 4 + r;
            const float yf = yr_dot[b] + ys;
            const size_t idx = (size_t)b * HIDDEN + i;
            const float ig = acc[0][mf][r] + yf * wi[0] + cb[0];
            const float fg = acc[1][mf][r] + yf * wi[1] + cb[1];
            const float gg = acc[2][mf][r] + yf * wi[2] + cb[2];
            const float og = acc[3][mf][r] + yf * wi[3] + cb[3];
            const float sn = sigmoidf(fg) * s_old[idx] + sigmoidf(ig) * tanhf(gg);
            const float dn = sigmoidf(og) * tanhf(sn);
            s_new[idx] = sn;
            sb_new[idx] = f2bf(sn);
            db_new[idx] = f2bf(dn);
            if (d_new != nullptr) d_new[idx] = dn;
        }
    }
}

// ===========================================================================
// COOPERATIVE PATH: persistent scan, 256 blocks, custom fast grid barrier.
// Block bx: m-tile = bx&31 (64 rows), n-tile = bx>>5 (64 cols).
// ===========================================================================
__global__ __launch_bounds__(256) void scan_coop(
        const unsigned short* __restrict__ dbb0, unsigned short* __restrict__ dbb1,
        const unsigned short* __restrict__ sbb0, unsigned short* __restrict__ sbb1,
        float* __restrict__ sbuf0, float* __restrict__ sbuf1,
        const float* __restrict__ s_init,
        const unsigned short* __restrict__ Wdb, const unsigned short* __restrict__ Whhb,
        const unsigned short* __restrict__ Gb, const float* __restrict__ vd,
        const float* __restrict__ Wih, const float* __restrict__ bih,
        const float* __restrict__ bhh, const float* __restrict__ yr_dot,
        const float* __restrict__ hw, const float* __restrict__ b00,
        float* __restrict__ lpart, float* __restrict__ y_out,
        float* __restrict__ d_out_f, float* __restrict__ s_out_f,
        unsigned* __restrict__ bar) {
    __shared__ __align__(16) short As[64 * LDT];
    __shared__ __align__(16) short Bwd[64 * LDT];
    __shared__ __align__(16) short Bwh[4][64 * LDT];
    __shared__ float red[2][64];
    __shared__ float smax[256], ssum[256], ssum2[256];

    unsigned* bar_cnt = bar;
    unsigned* bar_gen = bar + 4;   // separate cachelines-ish (16B apart; distinct words)
    unsigned lgen = 0;

    const int tid = threadIdx.x;
    const int wave = tid >> 6, lane = tid & 63;
    const int wm = wave >> 1, wn = wave & 1;
    const int quad = lane >> 4, lr = lane & 15, qk = quad * 8;
    const int bx = blockIdx.x;
    const int m0 = (bx & 31) * 64;
    const int nt = bx >> 5;              // 0..7
    const int n0 = nt * 64;
    const int arow = tid >> 2, aseg = tid & 3;

    const float b00v = b00[0];
    int icolv[2];
    float vdv[2], wi[4][2], cbv[4][2];
#pragma unroll
    for (int nf = 0; nf < 2; ++nf) {
        icolv[nf] = n0 + wn * 32 + nf * 16 + lr;
        vdv[nf] = vd[icolv[nf]];
#pragma unroll
        for (int g = 0; g < 4; ++g) {
            wi[g][nf]  = Wih[g * HIDDEN + icolv[nf]];
            cbv[g][nf] = bih[g * HIDDEN + icolv[nf]] + bhh[g * HIDDEN + icolv[nf]];
        }
    }
    float yrc[2][4];
#pragma unroll
    for (int mf = 0; mf < 2; ++mf)
#pragma unroll
        for (int r = 0; r < 4; ++r)
            yrc[mf][r] = yr_dot[m0 + wm * 32 + mf * 16 + quad * 4 + r];

    float ctw = 0.f;   // identical in every block (deterministic redundant compute)

    for (int t = 0; t < WINDOW; ++t) {
        const int rp = t & 1;
        const unsigned short* dcur = rp ? dbb1 : dbb0;
        const unsigned short* scur = rp ? sbb1 : sbb0;
        unsigned short* dnxt = rp ? (unsigned short*)dbb0 : dbb1;
        unsigned short* snxt = rp ? (unsigned short*)sbb0 : sbb1;
        const float* s_old = (t == 0) ? s_init : (rp ? sbuf0 : sbuf1);
        float* s_new = (t == WINDOW - 1) ? s_out_f : (rp ? sbuf1 : sbuf0);
        const unsigned short* Gtb = Gb + (size_t)t * BH;

        // ---------- Phase A: fused s1 (K=1024) + gates (K=512) GEMMs ----------
        floatx4 acc1[2][2] = {};
        floatx4 accg[4][2][2] = {};
        for (int k0 = 0; k0 < HIDDEN; k0 += 32) {
            *(float4*)(As + arow * LDT + aseg * 8) =
                *(const float4*)(dcur + (size_t)(m0 + arow) * HIDDEN + k0 + aseg * 8);
            *(float4*)(Bwd + arow * LDT + aseg * 8) =
                *(const float4*)(Wdb + (size_t)(n0 + arow) * (2 * HIDDEN) + k0 + aseg * 8);
#pragma unroll
            for (int j = 0; j < 4; ++j) {
                const int c = tid + 256 * j;          // 1024 chunks: 4g x 64row x 4seg
                const int g = c >> 8, cc = c & 255, row = cc >> 2, seg = cc & 3;
                *(float4*)(Bwh[g] + row * LDT + seg * 8) =
                    *(const float4*)(Whhb + (size_t)(g * HIDDEN + n0 + row) * HIDDEN + k0 + seg * 8);
            }
            __syncthreads();
            short8 a0  = *(const short8*)(As + (wm * 32 + lr) * LDT + qk);
            short8 a1  = *(const short8*)(As + (wm * 32 + 16 + lr) * LDT + qk);
            short8 bw0 = *(const short8*)(Bwd + (wn * 32 + lr) * LDT + qk);
            short8 bw1 = *(const short8*)(Bwd + (wn * 32 + 16 + lr) * LDT + qk);
            acc1[0][0] = mfma16(a0, bw0, acc1[0][0]);
            acc1[0][1] = mfma16(a0, bw1, acc1[0][1]);
            acc1[1][0] = mfma16(a1, bw0, acc1[1][0]);
            acc1[1][1] = mfma16(a1, bw1, acc1[1][1]);
#pragma unroll
            for (int g = 0; g < 4; ++g) {
                short8 bh0 = *(const short8*)(Bwh[g] + (wn * 32 + lr) * LDT + qk);
                short8 bh1 = *(const short8*)(Bwh[g] + (wn * 32 + 16 + lr) * LDT + qk);
                accg[g][0][0] = mfma16(a0, bh0, accg[g][0][0]);
                accg[g][0][1] = mfma16(a0, bh1, accg[g][0][1]);
                accg[g][1][0] = mfma16(a1, bh0, accg[g][1][0]);
                accg[g][1][1] = mfma16(a1, bh1, accg[g][1][1]);
            }
            __syncthreads();
        }
        // pass 1: A = s0, Wd cols [512,1024) (s1 only)
        for (int k0 = 0; k0 < HIDDEN; k0 += 32) {
            *(float4*)(As + arow * LDT + aseg * 8) =
                *(const float4*)(scur + (size_t)(m0 + arow) * HIDDEN + k0 + aseg * 8);
            *(float4*)(Bwd + arow * LDT + aseg * 8) =
                *(const float4*)(Wdb + (size_t)(n0 + arow) * (2 * HIDDEN) + HIDDEN + k0 + aseg * 8);
            __syncthreads();
            short8 a0  = *(const short8*)(As + (wm * 32 + lr) * LDT + qk);
            short8 a1  = *(const short8*)(As + (wm * 32 + 16 + lr) * LDT + qk);
            short8 bw0 = *(const short8*)(Bwd + (wn * 32 + lr) * LDT + qk);
            short8 bw1 = *(const short8*)(Bwd + (wn * 32 + 16 + lr) * LDT + qk);
            acc1[0][0] = mfma16(a0, bw0, acc1[0][0]);
            acc1[0][1] = mfma16(a0, bw1, acc1[0][1]);
            acc1[1][0] = mfma16(a1, bw0, acc1[1][0]);
            acc1[1][1] = mfma16(a1, bw1, acc1[1][1]);
            __syncthreads();
        }
        // s1 epilogue: tanh(.+Gt)*vd, reduce over this block's 64 cols
#pragma unroll
        for (int mf = 0; mf < 2; ++mf) {
            float rs[4];
#pragma unroll
            for (int r = 0; r < 4; ++r) {
                const int b = m0 + wm * 32 + mf * 16 + quad * 4 + r;
                float v = 0.f;
#pragma unroll
                for (int nf = 0; nf < 2; ++nf)
                    v += tanhf(acc1[mf][nf][r] + bf2f(Gtb[(size_t)b * HIDDEN + icolv[nf]])) * vdv[nf];
                for (int msk = 1; msk < 16; msk <<= 1) v += __shfl_xor(v, msk, 16);
                rs[r] = v;
            }
            if (lr == 0)
#pragma unroll
                for (int r = 0; r < 4; ++r)
                    red[wn][wm * 32 + mf * 16 + quad * 4 + r] = rs[r];
        }
        __syncthreads();
        if (tid < 64)
            lpart[(size_t)nt * BATCH + m0 + tid] = red[0][tid] + red[1][tid];

        grid_barrier(bar_cnt, bar_gen, lgen);

        // ---------- Phase B: redundant softmax + ctw recursion ----------
        const int bb = tid * 8;
        float l[8] = {0.f, 0.f, 0.f, 0.f, 0.f, 0.f, 0.f, 0.f};
#pragma unroll
        for (int p = 0; p < 8; ++p) {
            const float4 u0 = *(const float4*)(lpart + (size_t)p * BATCH + bb);
            const float4 u1 = *(const float4*)(lpart + (size_t)p * BATCH + bb + 4);
            l[0] += u0.x; l[1] += u0.y; l[2] += u0.z; l[3] += u0.w;
            l[4] += u1.x; l[5] += u1.y; l[6] += u1.z; l[7] += u1.w;
        }
        float mx = l[0];
#pragma unroll
        for (int j = 1; j < 8; ++j) mx = fmaxf(mx, l[j]);
        smax[tid] = mx;
        __syncthreads();
        for (int o = 128; o; o >>= 1) {
            if (tid < o) smax[tid] = fmaxf(smax[tid], smax[tid + o]);
            __syncthreads();
        }
        const float M = smax[0];
        const float* hwt = hw + (size_t)t * BATCH;
        const float4 h0 = *(const float4*)(hwt + bb);
        const float4 h1 = *(const float4*)(hwt + bb + 4);
        const float hv[8] = {h0.x, h0.y, h0.z, h0.w, h1.x, h1.y, h1.z, h1.w};
        float se = 0.f, sh = 0.f;
#pragma unroll
        for (int j = 0; j < 8; ++j) {
            const float e = expf(l[j] - M);
            se += e;
            sh += e * hv[j];
        }
        ssum[tid] = se; ssum2[tid] = sh;
        __syncthreads();
        for (int o = 128; o; o >>= 1) {
            if (tid < o) { ssum[tid] += ssum[tid + o]; ssum2[tid] += ssum2[tid + o]; }
            __syncthreads();
        }
        ctw += ssum2[0] / ssum[0];
        const float ys = ctw + b00v;

        // ---------- Phase C: gates epilogue + LSTM update ----------
#pragma unroll
        for (int nf = 0; nf < 2; ++nf) {
#pragma unroll
            for (int mf = 0; mf < 2; ++mf) {
#pragma unroll
                for (int r = 0; r < 4; ++r) {
                    const int b = m0 + wm * 32 + mf * 16 + quad * 4 + r;
                    const float yf = yrc[mf][r] + ys;
                    const size_t idx = (size_t)b * HIDDEN + icolv[nf];
                    const float ig = accg[0][mf][nf][r] + yf * wi[0][nf] + cbv[0][nf];
                    const float fg = accg[1][mf][nf][r] + yf * wi[1][nf] + cbv[1][nf];
                    const float gg = accg[2][mf][nf][r] + yf * wi[2][nf] + cbv[2][nf];
                    const float og = accg[3][mf][nf][r] + yf * wi[3][nf] + cbv[3][nf];
                    const float sn = sigmoidf(fg) * s_old[idx] + sigmoidf(ig) * tanhf(gg);
                    const float dn = sigmoidf(og) * tanhf(sn);
                    s_new[idx] = sn;
                    snxt[idx] = f2bf(sn);
                    dnxt[idx] = f2bf(dn);
                    if (t == WINDOW - 1) d_out_f[idx] = dn;
                }
            }
        }
        if (t == WINDOW - 1 && nt == 0 && tid < 64)
            y_out[m0 + tid] = yr_dot[m0 + tid] + ys;

        grid_barrier(bar_cnt, bar_gen, lgen);
    }
}

// ---------------------------------------------------------------------------
extern "C" void kernel_launch(void* const* d_in, const int* in_sizes, int n_in,
                              void* d_out, int out_size, void* d_ws, size_t ws_size,
                              hipStream_t stream) {
    const float* Z      = (const float*)d_in[0];
    const float* d_init = (const float*)d_in[1];
    const float* s_init = (const float*)d_in[2];
    const float* y_real = (const float*)d_in[3];
    const float* vd     = (const float*)d_in[4];
    const float* Wd     = (const float*)d_in[5];
    const float* Ud     = (const float*)d_in[6];
    const float* w      = (const float*)d_in[7];
    const float* b00    = (const float*)d_in[8];
    const float* conv_w = (const float*)d_in[9];
    const float* conv_b = (const float*)d_in[10];
    const float* Wih    = (const float*)d_in[11];
    const float* Whh    = (const float*)d_in[12];
    const float* bih    = (const float*)d_in[13];
    const float* bhh    = (const float*)d_in[14];

    float* ws = (float*)d_ws;
    size_t off = 0;
    unsigned short* Htb = (unsigned short*)(ws + off);  off += (size_t)WINDOW * BH / 2;
    unsigned short* Gb  = (unsigned short*)(ws + off);  off += (size_t)WINDOW * BH / 2;
    unsigned short* dbb0 = (unsigned short*)(ws + off);  off += BH / 2;
    unsigned short* dbb1 = (unsigned short*)(ws + off);  off += BH / 2;
    unsigned short* sbb0 = (unsigned short*)(ws + off);  off += BH / 2;
    unsigned short* sbb1 = (unsigned short*)(ws + off);  off += BH / 2;
    float* sbuf0 = ws + off;  off += BH;
    float* sbuf1 = ws + off;  off += BH;
    unsigned short* Wdb  = (unsigned short*)(ws + off);  off += (size_t)HIDDEN * 2 * HIDDEN / 2;
    unsigned short* Udb  = (unsigned short*)(ws + off);  off += (size_t)HIDDEN * HIDDEN / 2;
    unsigned short* Whhb = (unsigned short*)(ws + off);  off += (size_t)H4 * HIDDEN / 2;
    float* hw     = ws + off;  off += (size_t)WINDOW * BATCH;
    float* lpart  = ws + off;  off += (size_t)16 * BATCH;
    float* yr_dot = ws + off;  off += BATCH;
    float* ctw    = ws + off;  off += 4;
    float* yscal  = ws + off;  off += 4;
    unsigned* bar = (unsigned*)(ws + off);  off += 8;

    float* out = (float*)d_out;
    float* y_out   = out;
    float* d_out_f = out + BATCH;
    float* s_out_f = out + BATCH + (size_t)BH;

    // --- one-time prep ---
    cvt5_kernel<<<3840, 256, 0, stream>>>(Wd, Wdb, Ud, Udb, Whh, Whhb,
                                          d_init, dbb0, s_init, sbb0);
    conv_kernel<<<BATCH, 256, 0, stream>>>(Z, conv_w, conv_b, (unsigned int*)Htb);
    hw_kernel<<<(WINDOW * BATCH) / 4, 256, 0, stream>>>(Htb, w, hw);
    {
        dim3 grid(HIDDEN / 64, (WINDOW * BATCH) / 64);
        g_gemm_mfma<<<grid, 256, 0, stream>>>(Htb, Udb, Gb);
    }
    init_kernel<<<8, 256, 0, stream>>>(y_real, w, yr_dot, ctw, bar);

    // --- cooperative persistent scan (256 blocks, custom barrier) ---
    const unsigned short* dbb0c = dbb0;
    const unsigned short* sbb0c = sbb0;
    void* args[] = {
        (void*)&dbb0c, (void*)&dbb1, (void*)&sbb0c, (void*)&sbb1,
        (void*)&sbuf0, (void*)&sbuf1, (void*)&s_init,
        (void*)&Wdb, (void*)&Whhb, (void*)&Gb, (void*)&vd,
        (void*)&Wih, (void*)&bih, (void*)&bhh, (void*)&yr_dot,
        (void*)&hw, (void*)&b00, (void*)&lpart, (void*)&y_out,
        (void*)&d_out_f, (void*)&s_out_f, (void*)&bar,
    };
    hipError_t cerr = hipLaunchCooperativeKernel((void*)scan_coop, dim3(GRIDB), dim3(256),
                                                 args, 0, stream);
    if (cerr != hipSuccess) {
        (void)hipGetLastError();   // clear sticky error state
        // --- fallback: proven round-4 3-launch scan ---
        const float* s_read = s_init;
        int pp = 0;
        for (int t = 0; t < WINDOW; ++t) {
            const unsigned short* Gtb = Gb + (size_t)t * BH;
            unsigned short* dbbs[2] = {dbb0, dbb1};
            unsigned short* sbbs[2] = {sbb0, sbb1};
            float* sbufs[2] = {sbuf0, sbuf1};
            s1_mfma<<<512, 256, 0, stream>>>(dbbs[pp], sbbs[pp], Wdb, Gtb, vd, lpart);
            mid_kernel<<<1, 1024, 0, stream>>>(lpart, hw + t * BATCH, ctw, b00, yscal,
                                               yr_dot, (t == WINDOW - 1) ? y_out : nullptr);
            float* s_w = (t == WINDOW - 1) ? s_out_f : sbufs[t & 1];
            float* d_w = (t == WINDOW - 1) ? d_out_f : nullptr;
            gates_lstm_mfma<<<512, 256, 0, stream>>>(dbbs[pp], Whhb, Wih, bih, bhh,
                                                     yr_dot, yscal, s_read, s_w, d_w,
                                                     sbbs[1 - pp], dbbs[1 - pp]);
            s_read = s_w;
            pp ^= 1;
        }
    }
}

// Round 8
// 1911.831 us; speedup vs baseline: 1.4158x; 1.3853x over previous
//
#include <hip/hip_runtime.h>
#include <math.h>

#define HIDDEN 512
#define WINDOW 24
#define KSZ 3
#define BATCH 2048
#define L_IN 514
#define H4 2048
#define LDT 40                    // padded LDS row stride (shorts) for 32-k tiles
#define BH (BATCH * HIDDEN)
#define GRIDB 256                 // persistent grid size (1 block/CU)
#define BAR_WORDS 4352            // 256 slots x 16 words + gen + pad

typedef short short8 __attribute__((ext_vector_type(8)));
typedef float floatx4 __attribute__((ext_vector_type(4)));

__device__ __forceinline__ floatx4 mfma16(short8 a, short8 b, floatx4 c) {
    return __builtin_amdgcn_mfma_f32_16x16x32_bf16(a, b, c, 0, 0, 0);
}
__device__ __forceinline__ unsigned short f2bf(float x) {
    union { float f; unsigned u; } v; v.f = x;
    unsigned r = v.u + 0x7fff + ((v.u >> 16) & 1);   // RTNE
    return (unsigned short)(r >> 16);
}
__device__ __forceinline__ float bf2f(unsigned short u) {
    union { unsigned u; float f; } v; v.u = ((unsigned)u) << 16;
    return v.f;
}
__device__ __forceinline__ float sigmoidf(float x) { return 1.f / (1.f + expf(-x)); }

// ---------------------------------------------------------------------------
// Distributed-arrival, relaxed-poll grid barrier.
//   - arrival: one RELAXED agent store per block to its own 64B-padded slot
//     (parallel, no RMW serialization; agent-scope atomics route to LLC).
//   - block 0: 256 threads poll the 256 slots with RELAXED loads (no
//     buffer_inv storm), then thread 0 publishes gen.
//   - spinners: RELAXED poll on gen; exactly one __threadfence() before
//     arrival (wbL2: release this block's writes) and one after release
//     (inv: acquire other blocks' writes) per block per barrier.
// ---------------------------------------------------------------------------
__device__ __forceinline__ void grid_barrier(unsigned* __restrict__ bar, unsigned& lgen) {
    unsigned* slots = bar;            // slot bx at bar[bx*16]
    unsigned* gen   = bar + 4096;
    const unsigned g = lgen + 1;
    __syncthreads();                  // all block stores issued (waitcnt before s_barrier)
    if (blockIdx.x == 0) {
        if (threadIdx.x == 0) {
            __threadfence();          // release: write back this block's L2
            __hip_atomic_store(&slots[0], g, __ATOMIC_RELAXED, __HIP_MEMORY_SCOPE_AGENT);
        }
        // 256 threads poll the 256 slots in parallel, relaxed
        while (__hip_atomic_load(&slots[threadIdx.x * 16], __ATOMIC_RELAXED,
                                 __HIP_MEMORY_SCOPE_AGENT) < g)
            __builtin_amdgcn_s_sleep(2);
        __syncthreads();              // all slots observed
        if (threadIdx.x == 0) {
            __hip_atomic_store(gen, g, __ATOMIC_RELAXED, __HIP_MEMORY_SCOPE_AGENT);
            __threadfence();          // acquire for block 0's subsequent reads
        }
        __syncthreads();
    } else {
        if (threadIdx.x == 0) {
            __threadfence();          // release this block's writes
            __hip_atomic_store(&slots[blockIdx.x * 16], g, __ATOMIC_RELAXED,
                               __HIP_MEMORY_SCOPE_AGENT);
            while (__hip_atomic_load(gen, __ATOMIC_RELAXED, __HIP_MEMORY_SCOPE_AGENT) < g)
                __builtin_amdgcn_s_sleep(2);
            __threadfence();          // acquire: invalidate stale L2
        }
        __syncthreads();
    }
    lgen = g;
}

// ---------------------------------------------------------------------------
// cvt5: fp32 -> bf16 for Wd, Ud, Whh, d_init, s_init
// ---------------------------------------------------------------------------
__global__ void cvt5_kernel(const float* __restrict__ s0, unsigned short* __restrict__ d0,
                            const float* __restrict__ s1, unsigned short* __restrict__ d1,
                            const float* __restrict__ s2, unsigned short* __restrict__ d2,
                            const float* __restrict__ s3, unsigned short* __restrict__ d3,
                            const float* __restrict__ s4, unsigned short* __restrict__ d4) {
    const int g = blockIdx.x * blockDim.x + threadIdx.x;   // one float4 per thread
    const float* src; unsigned short* dst; int off;
    if      (g < 131072) { src = s0; dst = d0; off = g; }
    else if (g < 196608) { src = s1; dst = d1; off = g - 131072; }
    else if (g < 458752) { src = s2; dst = d2; off = g - 196608; }
    else if (g < 720896) { src = s3; dst = d3; off = g - 458752; }
    else if (g < 983040) { src = s4; dst = d4; off = g - 720896; }
    else return;
    float4 v = ((const float4*)src)[off];
    uint2 u;
    u.x = (unsigned)f2bf(v.x) | ((unsigned)f2bf(v.y) << 16);
    u.y = (unsigned)f2bf(v.z) | ((unsigned)f2bf(v.w) << 16);
    ((uint2*)dst)[off] = u;
}

// ---------------------------------------------------------------------------
// conv1d(2->24, k=3, valid) + bias + relu -> Htb bf16 [t][b][i]
// ---------------------------------------------------------------------------
__global__ void conv_kernel(const float* __restrict__ Z, const float* __restrict__ conv_w,
                            const float* __restrict__ conv_b,
                            unsigned int* __restrict__ Htu) {
    __shared__ float cw[WINDOW * 6];
    __shared__ float cb[WINDOW];
    const int b = blockIdx.x;
    if (threadIdx.x < WINDOW * 6) cw[threadIdx.x] = conv_w[threadIdx.x];
    if (threadIdx.x < WINDOW) cb[threadIdx.x] = conv_b[threadIdx.x];
    __syncthreads();
    const float* z0 = Z + (size_t)b * L_IN;
    const float* z1 = z0 + (size_t)BATCH * L_IN;
    const int i0 = threadIdx.x * 2;
    const float a0 = z0[i0], a1 = z0[i0 + 1], a2 = z0[i0 + 2], a3 = z0[i0 + 3];
    const float c0 = z1[i0], c1 = z1[i0 + 1], c2 = z1[i0 + 2], c3 = z1[i0 + 3];
#pragma unroll
    for (int o = 0; o < WINDOW; ++o) {
        const float* wc = cw + o * 6;
        float v0 = fmaxf(cb[o] + a0 * wc[0] + a1 * wc[1] + a2 * wc[2]
                               + c0 * wc[3] + c1 * wc[4] + c2 * wc[5], 0.f);
        float v1 = fmaxf(cb[o] + a1 * wc[0] + a2 * wc[1] + a3 * wc[2]
                               + c1 * wc[3] + c2 * wc[4] + c3 * wc[5], 0.f);
        Htu[((size_t)o * BATCH + b) * 256 + threadIdx.x] =
            (unsigned)f2bf(v0) | ((unsigned)f2bf(v1) << 16);
    }
}

// ---------------------------------------------------------------------------
// hw[t][b] = H_t[b,:] . w[24:]
// ---------------------------------------------------------------------------
__global__ void hw_kernel(const unsigned short* __restrict__ Htb,
                          const float* __restrict__ w, float* __restrict__ hw) {
    const int row = blockIdx.x * 4 + (threadIdx.x >> 6);
    const int lane = threadIdx.x & 63;
    short8 v = *(const short8*)(Htb + (size_t)row * HIDDEN + lane * 8);
    float acc = 0.f;
#pragma unroll
    for (int j = 0; j < 8; ++j)
        acc += bf2f((unsigned short)v[j]) * w[WINDOW + lane * 8 + j];
    for (int m = 32; m; m >>= 1) acc += __shfl_xor(acc, m, 64);
    if (lane == 0) hw[row] = acc;
}

// ---------------------------------------------------------------------------
// Gb = Htb[49152 x 512] @ Udb^T  (bf16 out)
// ---------------------------------------------------------------------------
__global__ __launch_bounds__(256) void g_gemm_mfma(const unsigned short* __restrict__ Htb,
                                                   const unsigned short* __restrict__ Udb,
                                                   unsigned short* __restrict__ Gb) {
    __shared__ __align__(16) short As[64 * LDT];
    __shared__ __align__(16) short Bs[64 * LDT];
    const int tid = threadIdx.x;
    const int wave = tid >> 6, lane = tid & 63;
    const int wm = wave >> 1, wn = wave & 1;
    const int quad = lane >> 4, lr = lane & 15, qk = quad * 8;
    const int n0 = blockIdx.x * 64, m0 = blockIdx.y * 64;
    const int arow = tid >> 2, aseg = tid & 3;
    floatx4 acc[2][2] = {};
    for (int k0 = 0; k0 < HIDDEN; k0 += 32) {
        *(float4*)(As + arow * LDT + aseg * 8) =
            *(const float4*)(Htb + (size_t)(m0 + arow) * HIDDEN + k0 + aseg * 8);
        *(float4*)(Bs + arow * LDT + aseg * 8) =
            *(const float4*)(Udb + (size_t)(n0 + arow) * HIDDEN + k0 + aseg * 8);
        __syncthreads();
        short8 a0 = *(const short8*)(As + (wm * 32 + lr) * LDT + qk);
        short8 a1 = *(const short8*)(As + (wm * 32 + 16 + lr) * LDT + qk);
        short8 b0 = *(const short8*)(Bs + (wn * 32 + lr) * LDT + qk);
        short8 b1 = *(const short8*)(Bs + (wn * 32 + 16 + lr) * LDT + qk);
        acc[0][0] = mfma16(a0, b0, acc[0][0]);
        acc[0][1] = mfma16(a0, b1, acc[0][1]);
        acc[1][0] = mfma16(a1, b0, acc[1][0]);
        acc[1][1] = mfma16(a1, b1, acc[1][1]);
        __syncthreads();
    }
#pragma unroll
    for (int mf = 0; mf < 2; ++mf)
#pragma unroll
        for (int nf = 0; nf < 2; ++nf)
#pragma unroll
            for (int r = 0; r < 4; ++r) {
                const int m = m0 + wm * 32 + mf * 16 + quad * 4 + r;
                const int n = n0 + wn * 32 + nf * 16 + lr;
                Gb[(size_t)m * HIDDEN + n] = f2bf(acc[mf][nf][r]);
            }
}

// ---------------------------------------------------------------------------
// init: yr_dot; zero ctw (fallback) and barrier state (coop)
// ---------------------------------------------------------------------------
__global__ void init_kernel(const float* __restrict__ y_real, const float* __restrict__ w,
                            float* __restrict__ yr_dot, float* __restrict__ ctw,
                            unsigned* __restrict__ bar) {
    const int tid = blockIdx.x * blockDim.x + threadIdx.x;
    if (tid < BATCH) {
        float s = 0.f;
#pragma unroll
        for (int j = 0; j < WINDOW; ++j) s += y_real[tid * WINDOW + j] * w[j];
        yr_dot[tid] = s;
    }
    if (tid == 0) ctw[0] = 0.f;
    for (int i = tid; i < BAR_WORDS; i += 2048) bar[i] = 0u;
}

// ===========================================================================
// FALLBACK PATH (round-4 proven kernels, 3 launches/step)
// ===========================================================================
__global__ __launch_bounds__(256) void s1_mfma(const unsigned short* __restrict__ db,
                                               const unsigned short* __restrict__ sb,
                                               const unsigned short* __restrict__ Wdb,
                                               const unsigned short* __restrict__ Gtb,
                                               const float* __restrict__ vd,
                                               float* __restrict__ lpart) {
    __shared__ __align__(16) short As[64 * LDT];
    __shared__ __align__(16) short Bs[32 * LDT];
    __shared__ float red[2][64];
    const int tid = threadIdx.x;
    const int wave = tid >> 6, lane = tid & 63;
    const int wm = wave >> 1, wn = wave & 1;
    const int quad = lane >> 4, lr = lane & 15, qk = quad * 8;
    const int m0 = (blockIdx.x & 31) * 64;
    const int nb = blockIdx.x >> 5;
    const int n0 = nb * 32;
    const int arow = tid >> 2, aseg = tid & 3;
    floatx4 acc[2] = {};
#pragma unroll
    for (int pass = 0; pass < 2; ++pass) {
        const unsigned short* A = pass ? sb : db;
        const unsigned short* B = Wdb + pass * HIDDEN;
        for (int k0 = 0; k0 < HIDDEN; k0 += 32) {
            *(float4*)(As + arow * LDT + aseg * 8) =
                *(const float4*)(A + (size_t)(m0 + arow) * HIDDEN + k0 + aseg * 8);
            if (tid < 128)
                *(float4*)(Bs + arow * LDT + aseg * 8) =
                    *(const float4*)(B + (size_t)(n0 + arow) * (2 * HIDDEN) + k0 + aseg * 8);
            __syncthreads();
            short8 a0 = *(const short8*)(As + (wm * 32 + lr) * LDT + qk);
            short8 a1 = *(const short8*)(As + (wm * 32 + 16 + lr) * LDT + qk);
            short8 b  = *(const short8*)(Bs + (wn * 16 + lr) * LDT + qk);
            acc[0] = mfma16(a0, b, acc[0]);
            acc[1] = mfma16(a1, b, acc[1]);
            __syncthreads();
        }
    }
#pragma unroll
    for (int mf = 0; mf < 2; ++mf) {
        float rs[4];
#pragma unroll
        for (int r = 0; r < 4; ++r) {
            const int b = m0 + wm * 32 + mf * 16 + quad * 4 + r;
            const int i = n0 + wn * 16 + lr;
            float v = tanhf(acc[mf][r] + bf2f(Gtb[(size_t)b * HIDDEN + i])) * vd[i];
            for (int msk = 1; msk < 16; msk <<= 1) v += __shfl_xor(v, msk, 16);
            rs[r] = v;
        }
        if (lr == 0)
#pragma unroll
            for (int r = 0; r < 4; ++r)
                red[wn][wm * 32 + mf * 16 + quad * 4 + r] = rs[r];
    }
    __syncthreads();
    if (tid < 64)
        lpart[(size_t)nb * BATCH + m0 + tid] = red[0][tid] + red[1][tid];
}

__global__ void mid_kernel(const float* __restrict__ lpart, const float* __restrict__ hw_t,
                           float* __restrict__ ctw, const float* __restrict__ b00,
                           float* __restrict__ yscal, const float* __restrict__ yr_dot,
                           float* __restrict__ y_out) {
    __shared__ float sm[1024];
    __shared__ float sm2[1024];
    __shared__ float ysh;
    const int tid = threadIdx.x;  // 1024
    float l0 = 0.f, l1 = 0.f;
#pragma unroll
    for (int p = 0; p < 16; ++p) {
        l0 += lpart[p * BATCH + tid];
        l1 += lpart[p * BATCH + tid + 1024];
    }
    sm[tid] = fmaxf(l0, l1);
    __syncthreads();
    for (int off = 512; off; off >>= 1) {
        if (tid < off) sm[tid] = fmaxf(sm[tid], sm[tid + off]);
        __syncthreads();
    }
    const float M = sm[0];
    __syncthreads();
    const float e0 = expf(l0 - M), e1 = expf(l1 - M);
    sm[tid]  = e0 + e1;
    sm2[tid] = e0 * hw_t[tid] + e1 * hw_t[1024 + tid];
    __syncthreads();
    for (int off = 512; off; off >>= 1) {
        if (tid < off) { sm[tid] += sm[tid + off]; sm2[tid] += sm2[tid + off]; }
        __syncthreads();
    }
    if (tid == 0) {
        const float c = ctw[0] + sm2[0] / sm[0];
        ctw[0] = c;
        ysh = c + b00[0];
        yscal[0] = ysh;
    }
    __syncthreads();
    if (y_out != nullptr) {
        const float ys = ysh;
        y_out[tid]        = yr_dot[tid] + ys;
        y_out[1024 + tid] = yr_dot[1024 + tid] + ys;
    }
}

__global__ __launch_bounds__(256) void gates_lstm_mfma(
        const unsigned short* __restrict__ db, const unsigned short* __restrict__ Whhb,
        const float* __restrict__ Wih, const float* __restrict__ bih,
        const float* __restrict__ bhh, const float* __restrict__ yr_dot,
        const float* __restrict__ yscal, const float* __restrict__ s_old,
        float* __restrict__ s_new, float* __restrict__ d_new,
        unsigned short* __restrict__ sb_new, unsigned short* __restrict__ db_new) {
    __shared__ __align__(16) short As[64 * LDT];
    __shared__ __align__(16) short Bs[4][32 * LDT];
    const int tid = threadIdx.x;
    const int wave = tid >> 6, lane = tid & 63;
    const int wm = wave >> 1, wn = wave & 1;
    const int quad = lane >> 4, lr = lane & 15, qk = quad * 8;
    const int m0 = (blockIdx.x & 31) * 64;
    const int n0 = (blockIdx.x >> 5) * 32;
    const int arow = tid >> 2, aseg = tid & 3;
    floatx4 acc[4][2] = {};
    for (int k0 = 0; k0 < HIDDEN; k0 += 32) {
        *(float4*)(As + arow * LDT + aseg * 8) =
            *(const float4*)(db + (size_t)(m0 + arow) * HIDDEN + k0 + aseg * 8);
#pragma unroll
        for (int j = 0; j < 2; ++j) {
            const int c = tid + 256 * j;
            const int g = c >> 7, cc = c & 127, row = cc >> 2, seg = cc & 3;
            *(float4*)(Bs[g] + row * LDT + seg * 8) =
                *(const float4*)(Whhb + (size_t)(g * HIDDEN + n0 + row) * HIDDEN + k0 + seg * 8);
        }
        __syncthreads();
        short8 a0 = *(const short8*)(As + (wm * 32 + lr) * LDT + qk);
        short8 a1 = *(const short8*)(As + (wm * 32 + 16 + lr) * LDT + qk);
#pragma unroll
        for (int g = 0; g < 4; ++g) {
            short8 b = *(const short8*)(Bs[g] + (wn * 16 + lr) * LDT + qk);
            acc[g][0] = mfma16(a0, b, acc[g][0]);
            acc[g][1] = mfma16(a1, b, acc[g][1]);
        }
        __syncthreads();
    }
    const float ys = yscal[0];
    const int i = n0 + wn * 16 + lr;
    float wi[4], cb[4];
#pragma unroll
    for (int g = 0; g < 4; ++g) {
        wi[g] = Wih[g * HIDDEN + i];
        cb[g] = bih[g * HIDDEN + i] + bhh[g * HIDDEN + i];
    }
#pragma unroll
    for (int mf = 0; mf < 2; ++mf) {
#pragma unroll
        for (int r = 0; r < 4; ++r) {
            const int b = m0 + wm * 32 + mf * 16 + quad * 4 + r;
            const float yf = yr_dot[b] + ys;
            const size_t idx = (size_t)b * HIDDEN + i;
            const float ig = acc[0][mf][r] + yf * wi[0] + cb[0];
            const float fg = acc[1][mf][r] + yf * wi[1] + cb[1];
            const float gg = acc[2][mf][r] + yf * wi[2] + cb[2];
            const float og = acc[3][mf][r] + yf * wi[3] + cb[3];
            const float sn = sigmoidf(fg) * s_old[idx] + sigmoidf(ig) * tanhf(gg);
            const float dn = sigmoidf(og) * tanhf(sn);
            s_new[idx] = sn;
            sb_new[idx] = f2bf(sn);
            db_new[idx] = f2bf(dn);
            if (d_new != nullptr) d_new[idx] = dn;
        }
    }
}

// ===========================================================================
// COOPERATIVE PATH: persistent scan, 256 blocks, distributed-arrival barrier.
// Block bx: m-tile = bx&31 (64 rows), n-tile = bx>>5 (64 cols).
// ===========================================================================
__global__ __launch_bounds__(256) void scan_coop(
        const unsigned short* __restrict__ dbb0, unsigned short* __restrict__ dbb1,
        const unsigned short* __restrict__ sbb0, unsigned short* __restrict__ sbb1,
        float* __restrict__ sbuf0, float* __restrict__ sbuf1,
        const float* __restrict__ s_init,
        const unsigned short* __restrict__ Wdb, const unsigned short* __restrict__ Whhb,
        const unsigned short* __restrict__ Gb, const float* __restrict__ vd,
        const float* __restrict__ Wih, const float* __restrict__ bih,
        const float* __restrict__ bhh, const float* __restrict__ yr_dot,
        const float* __restrict__ hw, const float* __restrict__ b00,
        float* __restrict__ lpart, float* __restrict__ y_out,
        float* __restrict__ d_out_f, float* __restrict__ s_out_f,
        unsigned* __restrict__ bar) {
    __shared__ __align__(16) short As[64 * LDT];
    __shared__ __align__(16) short Bwd[64 * LDT];
    __shared__ __align__(16) short Bwh[4][64 * LDT];
    __shared__ float red[2][64];
    __shared__ float smax[256], ssum[256], ssum2[256];

    unsigned lgen = 0;

    const int tid = threadIdx.x;
    const int wave = tid >> 6, lane = tid & 63;
    const int wm = wave >> 1, wn = wave & 1;
    const int quad = lane >> 4, lr = lane & 15, qk = quad * 8;
    const int bx = blockIdx.x;
    const int m0 = (bx & 31) * 64;
    const int nt = bx >> 5;              // 0..7
    const int n0 = nt * 64;
    const int arow = tid >> 2, aseg = tid & 3;

    const float b00v = b00[0];
    int icolv[2];
    float vdv[2], wi[4][2], cbv[4][2];
#pragma unroll
    for (int nf = 0; nf < 2; ++nf) {
        icolv[nf] = n0 + wn * 32 + nf * 16 + lr;
        vdv[nf] = vd[icolv[nf]];
#pragma unroll
        for (int g = 0; g < 4; ++g) {
            wi[g][nf]  = Wih[g * HIDDEN + icolv[nf]];
            cbv[g][nf] = bih[g * HIDDEN + icolv[nf]] + bhh[g * HIDDEN + icolv[nf]];
        }
    }
    float yrc[2][4];
#pragma unroll
    for (int mf = 0; mf < 2; ++mf)
#pragma unroll
        for (int r = 0; r < 4; ++r)
            yrc[mf][r] = yr_dot[m0 + wm * 32 + mf * 16 + quad * 4 + r];

    float ctw = 0.f;   // identical in every block (deterministic redundant compute)

    for (int t = 0; t < WINDOW; ++t) {
        const int rp = t & 1;
        const unsigned short* dcur = rp ? dbb1 : dbb0;
        const unsigned short* scur = rp ? sbb1 : sbb0;
        unsigned short* dnxt = rp ? (unsigned short*)dbb0 : dbb1;
        unsigned short* snxt = rp ? (unsigned short*)sbb0 : sbb1;
        const float* s_old = (t == 0) ? s_init : (rp ? sbuf0 : sbuf1);
        float* s_new = (t == WINDOW - 1) ? s_out_f : (rp ? sbuf1 : sbuf0);
        const unsigned short* Gtb = Gb + (size_t)t * BH;

        // ---------- Phase A: fused s1 (K=1024) + gates (K=512) GEMMs ----------
        floatx4 acc1[2][2] = {};
        floatx4 accg[4][2][2] = {};
        for (int k0 = 0; k0 < HIDDEN; k0 += 32) {
            *(float4*)(As + arow * LDT + aseg * 8) =
                *(const float4*)(dcur + (size_t)(m0 + arow) * HIDDEN + k0 + aseg * 8);
            *(float4*)(Bwd + arow * LDT + aseg * 8) =
                *(const float4*)(Wdb + (size_t)(n0 + arow) * (2 * HIDDEN) + k0 + aseg * 8);
#pragma unroll
            for (int j = 0; j < 4; ++j) {
                const int c = tid + 256 * j;          // 1024 chunks: 4g x 64row x 4seg
                const int g = c >> 8, cc = c & 255, row = cc >> 2, seg = cc & 3;
                *(float4*)(Bwh[g] + row * LDT + seg * 8) =
                    *(const float4*)(Whhb + (size_t)(g * HIDDEN + n0 + row) * HIDDEN + k0 + seg * 8);
            }
            __syncthreads();
            short8 a0  = *(const short8*)(As + (wm * 32 + lr) * LDT + qk);
            short8 a1  = *(const short8*)(As + (wm * 32 + 16 + lr) * LDT + qk);
            short8 bw0 = *(const short8*)(Bwd + (wn * 32 + lr) * LDT + qk);
            short8 bw1 = *(const short8*)(Bwd + (wn * 32 + 16 + lr) * LDT + qk);
            acc1[0][0] = mfma16(a0, bw0, acc1[0][0]);
            acc1[0][1] = mfma16(a0, bw1, acc1[0][1]);
            acc1[1][0] = mfma16(a1, bw0, acc1[1][0]);
            acc1[1][1] = mfma16(a1, bw1, acc1[1][1]);
#pragma unroll
            for (int g = 0; g < 4; ++g) {
                short8 bh0 = *(const short8*)(Bwh[g] + (wn * 32 + lr) * LDT + qk);
                short8 bh1 = *(const short8*)(Bwh[g] + (wn * 32 + 16 + lr) * LDT + qk);
                accg[g][0][0] = mfma16(a0, bh0, accg[g][0][0]);
                accg[g][0][1] = mfma16(a0, bh1, accg[g][0][1]);
                accg[g][1][0] = mfma16(a1, bh0, accg[g][1][0]);
                accg[g][1][1] = mfma16(a1, bh1, accg[g][1][1]);
            }
            __syncthreads();
        }
        // pass 1: A = s0, Wd cols [512,1024) (s1 only)
        for (int k0 = 0; k0 < HIDDEN; k0 += 32) {
            *(float4*)(As + arow * LDT + aseg * 8) =
                *(const float4*)(scur + (size_t)(m0 + arow) * HIDDEN + k0 + aseg * 8);
            *(float4*)(Bwd + arow * LDT + aseg * 8) =
                *(const float4*)(Wdb + (size_t)(n0 + arow) * (2 * HIDDEN) + HIDDEN + k0 + aseg * 8);
            __syncthreads();
            short8 a0  = *(const short8*)(As + (wm * 32 + lr) * LDT + qk);
            short8 a1  = *(const short8*)(As + (wm * 32 + 16 + lr) * LDT + qk);
            short8 bw0 = *(const short8*)(Bwd + (wn * 32 + lr) * LDT + qk);
            short8 bw1 = *(const short8*)(Bwd + (wn * 32 + 16 + lr) * LDT + qk);
            acc1[0][0] = mfma16(a0, bw0, acc1[0][0]);
            acc1[0][1] = mfma16(a0, bw1, acc1[0][1]);
            acc1[1][0] = mfma16(a1, bw0, acc1[1][0]);
            acc1[1][1] = mfma16(a1, bw1, acc1[1][1]);
            __syncthreads();
        }
        // s1 epilogue: tanh(.+Gt)*vd, reduce over this block's 64 cols
#pragma unroll
        for (int mf = 0; mf < 2; ++mf) {
            float rs[4];
#pragma unroll
            for (int r = 0; r < 4; ++r) {
                const int b = m0 + wm * 32 + mf * 16 + quad * 4 + r;
                float v = 0.f;
#pragma unroll
                for (int nf = 0; nf < 2; ++nf)
                    v += tanhf(acc1[mf][nf][r] + bf2f(Gtb[(size_t)b * HIDDEN + icolv[nf]])) * vdv[nf];
                for (int msk = 1; msk < 16; msk <<= 1) v += __shfl_xor(v, msk, 16);
                rs[r] = v;
            }
            if (lr == 0)
#pragma unroll
                for (int r = 0; r < 4; ++r)
                    red[wn][wm * 32 + mf * 16 + quad * 4 + r] = rs[r];
        }
        __syncthreads();
        if (tid < 64)
            lpart[(size_t)nt * BATCH + m0 + tid] = red[0][tid] + red[1][tid];

        grid_barrier(bar, lgen);

        // ---------- Phase B: redundant softmax + ctw recursion ----------
        const int bb = tid * 8;
        float l[8] = {0.f, 0.f, 0.f, 0.f, 0.f, 0.f, 0.f, 0.f};
#pragma unroll
        for (int p = 0; p < 8; ++p) {
            const float4 u0 = *(const float4*)(lpart + (size_t)p * BATCH + bb);
            const float4 u1 = *(const float4*)(lpart + (size_t)p * BATCH + bb + 4);
            l[0] += u0.x; l[1] += u0.y; l[2] += u0.z; l[3] += u0.w;
            l[4] += u1.x; l[5] += u1.y; l[6] += u1.z; l[7] += u1.w;
        }
        float mx = l[0];
#pragma unroll
        for (int j = 1; j < 8; ++j) mx = fmaxf(mx, l[j]);
        smax[tid] = mx;
        __syncthreads();
        for (int o = 128; o; o >>= 1) {
            if (tid < o) smax[tid] = fmaxf(smax[tid], smax[tid + o]);
            __syncthreads();
        }
        const float M = smax[0];
        const float* hwt = hw + (size_t)t * BATCH;
        const float4 h0 = *(const float4*)(hwt + bb);
        const float4 h1 = *(const float4*)(hwt + bb + 4);
        const float hv[8] = {h0.x, h0.y, h0.z, h0.w, h1.x, h1.y, h1.z, h1.w};
        float se = 0.f, sh = 0.f;
#pragma unroll
        for (int j = 0; j < 8; ++j) {
            const float e = expf(l[j] - M);
            se += e;
            sh += e * hv[j];
        }
        ssum[tid] = se; ssum2[tid] = sh;
        __syncthreads();
        for (int o = 128; o; o >>= 1) {
            if (tid < o) { ssum[tid] += ssum[tid + o]; ssum2[tid] += ssum2[tid + o]; }
            __syncthreads();
        }
        ctw += ssum2[0] / ssum[0];
        const float ys = ctw + b00v;

        // ---------- Phase C: gates epilogue + LSTM update ----------
#pragma unroll
        for (int nf = 0; nf < 2; ++nf) {
#pragma unroll
            for (int mf = 0; mf < 2; ++mf) {
#pragma unroll
                for (int r = 0; r < 4; ++r) {
                    const int b = m0 + wm * 32 + mf * 16 + quad * 4 + r;
                    const float yf = yrc[mf][r] + ys;
                    const size_t idx = (size_t)b * HIDDEN + icolv[nf];
                    const float ig = accg[0][mf][nf][r] + yf * wi[0][nf] + cbv[0][nf];
                    const float fg = accg[1][mf][nf][r] + yf * wi[1][nf] + cbv[1][nf];
                    const float gg = accg[2][mf][nf][r] + yf * wi[2][nf] + cbv[2][nf];
                    const float og = accg[3][mf][nf][r] + yf * wi[3][nf] + cbv[3][nf];
                    const float sn = sigmoidf(fg) * s_old[idx] + sigmoidf(ig) * tanhf(gg);
                    const float dn = sigmoidf(og) * tanhf(sn);
                    s_new[idx] = sn;
                    snxt[idx] = f2bf(sn);
                    dnxt[idx] = f2bf(dn);
                    if (t == WINDOW - 1) d_out_f[idx] = dn;
                }
            }
        }
        if (t == WINDOW - 1 && nt == 0 && tid < 64)
            y_out[m0 + tid] = yr_dot[m0 + tid] + ys;

        grid_barrier(bar, lgen);
    }
}

// ---------------------------------------------------------------------------
extern "C" void kernel_launch(void* const* d_in, const int* in_sizes, int n_in,
                              void* d_out, int out_size, void* d_ws, size_t ws_size,
                              hipStream_t stream) {
    const float* Z      = (const float*)d_in[0];
    const float* d_init = (const float*)d_in[1];
    const float* s_init = (const float*)d_in[2];
    const float* y_real = (const float*)d_in[3];
    const float* vd     = (const float*)d_in[4];
    const float* Wd     = (const float*)d_in[5];
    const float* Ud     = (const float*)d_in[6];
    const float* w      = (const float*)d_in[7];
    const float* b00    = (const float*)d_in[8];
    const float* conv_w = (const float*)d_in[9];
    const float* conv_b = (const float*)d_in[10];
    const float* Wih    = (const float*)d_in[11];
    const float* Whh    = (const float*)d_in[12];
    const float* bih    = (const float*)d_in[13];
    const float* bhh    = (const float*)d_in[14];

    float* ws = (float*)d_ws;
    size_t off = 0;
    unsigned short* Htb = (unsigned short*)(ws + off);  off += (size_t)WINDOW * BH / 2;
    unsigned short* Gb  = (unsigned short*)(ws + off);  off += (size_t)WINDOW * BH / 2;
    unsigned short* dbb0 = (unsigned short*)(ws + off);  off += BH / 2;
    unsigned short* dbb1 = (unsigned short*)(ws + off);  off += BH / 2;
    unsigned short* sbb0 = (unsigned short*)(ws + off);  off += BH / 2;
    unsigned short* sbb1 = (unsigned short*)(ws + off);  off += BH / 2;
    float* sbuf0 = ws + off;  off += BH;
    float* sbuf1 = ws + off;  off += BH;
    unsigned short* Wdb  = (unsigned short*)(ws + off);  off += (size_t)HIDDEN * 2 * HIDDEN / 2;
    unsigned short* Udb  = (unsigned short*)(ws + off);  off += (size_t)HIDDEN * HIDDEN / 2;
    unsigned short* Whhb = (unsigned short*)(ws + off);  off += (size_t)H4 * HIDDEN / 2;
    float* hw     = ws + off;  off += (size_t)WINDOW * BATCH;
    float* lpart  = ws + off;  off += (size_t)16 * BATCH;
    float* yr_dot = ws + off;  off += BATCH;
    float* ctw    = ws + off;  off += 4;
    float* yscal  = ws + off;  off += 4;
    unsigned* bar = (unsigned*)(ws + off);  off += BAR_WORDS;

    float* out = (float*)d_out;
    float* y_out   = out;
    float* d_out_f = out + BATCH;
    float* s_out_f = out + BATCH + (size_t)BH;

    // --- one-time prep ---
    cvt5_kernel<<<3840, 256, 0, stream>>>(Wd, Wdb, Ud, Udb, Whh, Whhb,
                                          d_init, dbb0, s_init, sbb0);
    conv_kernel<<<BATCH, 256, 0, stream>>>(Z, conv_w, conv_b, (unsigned int*)Htb);
    hw_kernel<<<(WINDOW * BATCH) / 4, 256, 0, stream>>>(Htb, w, hw);
    {
        dim3 grid(HIDDEN / 64, (WINDOW * BATCH) / 64);
        g_gemm_mfma<<<grid, 256, 0, stream>>>(Htb, Udb, Gb);
    }
    init_kernel<<<8, 256, 0, stream>>>(y_real, w, yr_dot, ctw, bar);

    // --- cooperative persistent scan (256 blocks, distributed barrier) ---
    const unsigned short* dbb0c = dbb0;
    const unsigned short* sbb0c = sbb0;
    void* args[] = {
        (void*)&dbb0c, (void*)&dbb1, (void*)&sbb0c, (void*)&sbb1,
        (void*)&sbuf0, (void*)&sbuf1, (void*)&s_init,
        (void*)&Wdb, (void*)&Whhb, (void*)&Gb, (void*)&vd,
        (void*)&Wih, (void*)&bih, (void*)&bhh, (void*)&yr_dot,
        (void*)&hw, (void*)&b00, (void*)&lpart, (void*)&y_out,
        (void*)&d_out_f, (void*)&s_out_f, (void*)&bar,
    };
    hipError_t cerr = hipLaunchCooperativeKernel((void*)scan_coop, dim3(GRIDB), dim3(256),
                                                 args, 0, stream);
    if (cerr != hipSuccess) {
        (void)hipGetLastError();   // clear sticky error state
        // --- fallback: proven round-4 3-launch scan ---
        const float* s_read = s_init;
        int pp = 0;
        for (int t = 0; t < WINDOW; ++t) {
            const unsigned short* Gtb = Gb + (size_t)t * BH;
            unsigned short* dbbs[2] = {dbb0, dbb1};
            unsigned short* sbbs[2] = {sbb0, sbb1};
            float* sbufs[2] = {sbuf0, sbuf1};
            s1_mfma<<<512, 256, 0, stream>>>(dbbs[pp], sbbs[pp], Wdb, Gtb, vd, lpart);
            mid_kernel<<<1, 1024, 0, stream>>>(lpart, hw + t * BATCH, ctw, b00, yscal,
                                               yr_dot, (t == WINDOW - 1) ? y_out : nullptr);
            float* s_w = (t == WINDOW - 1) ? s_out_f : sbufs[t & 1];
            float* d_w = (t == WINDOW - 1) ? d_out_f : nullptr;
            gates_lstm_mfma<<<512, 256, 0, stream>>>(dbbs[pp], Whhb, Wih, bih, bhh,
                                                     yr_dot, yscal, s_read, s_w, d_w,
                                                     sbbs[1 - pp], dbbs[1 - pp]);
            s_read = s_w;
            pp ^= 1;
        }
    }
}

// Round 9
// 1538.858 us; speedup vs baseline: 1.7590x; 1.2424x over previous
//
#include <hip/hip_runtime.h>
#include <math.h>

#define HIDDEN 512
#define WINDOW 24
#define KSZ 3
#define BATCH 2048
#define L_IN 514
#define H4 2048
#define LDT 40                    // padded LDS row stride (shorts) for 32-k tiles
#define BH (BATCH * HIDDEN)
#define GRIDB 256                 // persistent grid size (1 block/CU)
// barrier state layout (unsigned words): slots 256x16 | xflag 8x16 | xgo 8x16 |
// regc 8 (+pad) | prologue cnt/gen
#define XFLAG_OFF 4096
#define XGO_OFF   (4096 + 128)
#define REG_OFF   (4096 + 256)
#define PB_OFF    (4096 + 256 + 16)
#define BAR_WORDS 4608

typedef short short8 __attribute__((ext_vector_type(8)));
typedef float floatx4 __attribute__((ext_vector_type(4)));

__device__ __forceinline__ floatx4 mfma16(short8 a, short8 b, floatx4 c) {
    return __builtin_amdgcn_mfma_f32_16x16x32_bf16(a, b, c, 0, 0, 0);
}
__device__ __forceinline__ unsigned short f2bf(float x) {
    union { float f; unsigned u; } v; v.f = x;
    unsigned r = v.u + 0x7fff + ((v.u >> 16) & 1);   // RTNE
    return (unsigned short)(r >> 16);
}
__device__ __forceinline__ float bf2f(unsigned short u) {
    union { unsigned u; float f; } v; v.u = ((unsigned)u) << 16;
    return v.f;
}
__device__ __forceinline__ float sigmoidf(float x) { return 1.f / (1.f + expf(-x)); }

__device__ __forceinline__ unsigned ld_rlx(unsigned* p) {
    return __hip_atomic_load(p, __ATOMIC_RELAXED, __HIP_MEMORY_SCOPE_AGENT);
}
__device__ __forceinline__ void st_rlx(unsigned* p, unsigned v) {
    __hip_atomic_store(p, v, __ATOMIC_RELAXED, __HIP_MEMORY_SCOPE_AGENT);
}

// ---------------------------------------------------------------------------
// Hierarchical XCD-aware grid barrier: 1 buffer_wbl2 + 1 L2 buffer_inv PER XCD
// per barrier (closers only); siblings do a cheap per-CU vL1 inv. Arrival via
// relaxed per-block slots (LLC). Safety: between closer's wbl2 and its inv no
// block has passed the barrier, so the L2 holds no new dirty lines.
// ---------------------------------------------------------------------------
__device__ __forceinline__ void xbarrier(unsigned* __restrict__ bar,
                                         const unsigned* __restrict__ livemask,
                                         int bx, int my_xcd, bool closer, unsigned& lgen) {
    unsigned* slots = bar;
    unsigned* xflag = bar + XFLAG_OFF;
    unsigned* xgo   = bar + XGO_OFF;
    const unsigned g = ++lgen;
    const int tid = threadIdx.x;
    __syncthreads();                           // vmcnt drained: stores are in this XCD's L2
    if (tid == 0) st_rlx(&slots[bx * 16], g);  // arrival (routes to LLC)
    if (closer) {
        while (ld_rlx(&slots[tid * 16]) < g) __builtin_amdgcn_s_sleep(1);
        __syncthreads();                       // all 256 arrivals observed
        if (tid == 0) {
            asm volatile("buffer_wbl2 sc1\n\ts_waitcnt vmcnt(0)" ::: "memory");
            st_rlx(&xflag[my_xcd * 16], g);    // this XCD's data now in LLC
        }
        if (tid < 8 && livemask[tid])
            while (ld_rlx(&xflag[tid * 16]) < g) __builtin_amdgcn_s_sleep(1);
        __syncthreads();                       // every live XCD flushed
        if (tid == 0) {
            asm volatile("buffer_inv sc1\n\ts_waitcnt vmcnt(0)" ::: "memory");
            st_rlx(&xgo[my_xcd * 16], g);      // L2 clean: release siblings
        }
    } else {
        if (tid == 0)
            while (ld_rlx(&xgo[my_xcd * 16]) < g) __builtin_amdgcn_s_sleep(1);
    }
    __syncthreads();
    asm volatile("buffer_inv\n\ts_waitcnt vmcnt(0)" ::: "memory");   // vL1 inv (per-CU)
    __syncthreads();
}

// ---------------------------------------------------------------------------
// cvt5: fp32 -> bf16 for Wd, Ud, Whh, d_init, s_init
// ---------------------------------------------------------------------------
__global__ void cvt5_kernel(const float* __restrict__ s0, unsigned short* __restrict__ d0,
                            const float* __restrict__ s1, unsigned short* __restrict__ d1,
                            const float* __restrict__ s2, unsigned short* __restrict__ d2,
                            const float* __restrict__ s3, unsigned short* __restrict__ d3,
                            const float* __restrict__ s4, unsigned short* __restrict__ d4) {
    const int g = blockIdx.x * blockDim.x + threadIdx.x;   // one float4 per thread
    const float* src; unsigned short* dst; int off;
    if      (g < 131072) { src = s0; dst = d0; off = g; }
    else if (g < 196608) { src = s1; dst = d1; off = g - 131072; }
    else if (g < 458752) { src = s2; dst = d2; off = g - 196608; }
    else if (g < 720896) { src = s3; dst = d3; off = g - 458752; }
    else if (g < 983040) { src = s4; dst = d4; off = g - 720896; }
    else return;
    float4 v = ((const float4*)src)[off];
    uint2 u;
    u.x = (unsigned)f2bf(v.x) | ((unsigned)f2bf(v.y) << 16);
    u.y = (unsigned)f2bf(v.z) | ((unsigned)f2bf(v.w) << 16);
    ((uint2*)dst)[off] = u;
}

// ---------------------------------------------------------------------------
// conv1d(2->24, k=3, valid) + bias + relu -> Htb bf16 [t][b][i]
// ---------------------------------------------------------------------------
__global__ void conv_kernel(const float* __restrict__ Z, const float* __restrict__ conv_w,
                            const float* __restrict__ conv_b,
                            unsigned int* __restrict__ Htu) {
    __shared__ float cw[WINDOW * 6];
    __shared__ float cb[WINDOW];
    const int b = blockIdx.x;
    if (threadIdx.x < WINDOW * 6) cw[threadIdx.x] = conv_w[threadIdx.x];
    if (threadIdx.x < WINDOW) cb[threadIdx.x] = conv_b[threadIdx.x];
    __syncthreads();
    const float* z0 = Z + (size_t)b * L_IN;
    const float* z1 = z0 + (size_t)BATCH * L_IN;
    const int i0 = threadIdx.x * 2;
    const float a0 = z0[i0], a1 = z0[i0 + 1], a2 = z0[i0 + 2], a3 = z0[i0 + 3];
    const float c0 = z1[i0], c1 = z1[i0 + 1], c2 = z1[i0 + 2], c3 = z1[i0 + 3];
#pragma unroll
    for (int o = 0; o < WINDOW; ++o) {
        const float* wc = cw + o * 6;
        float v0 = fmaxf(cb[o] + a0 * wc[0] + a1 * wc[1] + a2 * wc[2]
                               + c0 * wc[3] + c1 * wc[4] + c2 * wc[5], 0.f);
        float v1 = fmaxf(cb[o] + a1 * wc[0] + a2 * wc[1] + a3 * wc[2]
                               + c1 * wc[3] + c2 * wc[4] + c3 * wc[5], 0.f);
        Htu[((size_t)o * BATCH + b) * 256 + threadIdx.x] =
            (unsigned)f2bf(v0) | ((unsigned)f2bf(v1) << 16);
    }
}

// ---------------------------------------------------------------------------
// hw[t][b] = H_t[b,:] . w[24:]
// ---------------------------------------------------------------------------
__global__ void hw_kernel(const unsigned short* __restrict__ Htb,
                          const float* __restrict__ w, float* __restrict__ hw) {
    const int row = blockIdx.x * 4 + (threadIdx.x >> 6);
    const int lane = threadIdx.x & 63;
    short8 v = *(const short8*)(Htb + (size_t)row * HIDDEN + lane * 8);
    float acc = 0.f;
#pragma unroll
    for (int j = 0; j < 8; ++j)
        acc += bf2f((unsigned short)v[j]) * w[WINDOW + lane * 8 + j];
    for (int m = 32; m; m >>= 1) acc += __shfl_xor(acc, m, 64);
    if (lane == 0) hw[row] = acc;
}

// ---------------------------------------------------------------------------
// Gb = Htb[49152 x 512] @ Udb^T  (bf16 out)
// ---------------------------------------------------------------------------
__global__ __launch_bounds__(256) void g_gemm_mfma(const unsigned short* __restrict__ Htb,
                                                   const unsigned short* __restrict__ Udb,
                                                   unsigned short* __restrict__ Gb) {
    __shared__ __align__(16) short As[64 * LDT];
    __shared__ __align__(16) short Bs[64 * LDT];
    const int tid = threadIdx.x;
    const int wave = tid >> 6, lane = tid & 63;
    const int wm = wave >> 1, wn = wave & 1;
    const int quad = lane >> 4, lr = lane & 15, qk = quad * 8;
    const int n0 = blockIdx.x * 64, m0 = blockIdx.y * 64;
    const int arow = tid >> 2, aseg = tid & 3;
    floatx4 acc[2][2] = {};
    for (int k0 = 0; k0 < HIDDEN; k0 += 32) {
        *(float4*)(As + arow * LDT + aseg * 8) =
            *(const float4*)(Htb + (size_t)(m0 + arow) * HIDDEN + k0 + aseg * 8);
        *(float4*)(Bs + arow * LDT + aseg * 8) =
            *(const float4*)(Udb + (size_t)(n0 + arow) * HIDDEN + k0 + aseg * 8);
        __syncthreads();
        short8 a0 = *(const short8*)(As + (wm * 32 + lr) * LDT + qk);
        short8 a1 = *(const short8*)(As + (wm * 32 + 16 + lr) * LDT + qk);
        short8 b0 = *(const short8*)(Bs + (wn * 32 + lr) * LDT + qk);
        short8 b1 = *(const short8*)(Bs + (wn * 32 + 16 + lr) * LDT + qk);
        acc[0][0] = mfma16(a0, b0, acc[0][0]);
        acc[0][1] = mfma16(a0, b1, acc[0][1]);
        acc[1][0] = mfma16(a1, b0, acc[1][0]);
        acc[1][1] = mfma16(a1, b1, acc[1][1]);
        __syncthreads();
    }
#pragma unroll
    for (int mf = 0; mf < 2; ++mf)
#pragma unroll
        for (int nf = 0; nf < 2; ++nf)
#pragma unroll
            for (int r = 0; r < 4; ++r) {
                const int m = m0 + wm * 32 + mf * 16 + quad * 4 + r;
                const int n = n0 + wn * 32 + nf * 16 + lr;
                Gb[(size_t)m * HIDDEN + n] = f2bf(acc[mf][nf][r]);
            }
}

// ---------------------------------------------------------------------------
// init: yr_dot; zero ctw (fallback) and barrier state (coop)
// ---------------------------------------------------------------------------
__global__ void init_kernel(const float* __restrict__ y_real, const float* __restrict__ w,
                            float* __restrict__ yr_dot, float* __restrict__ ctw,
                            unsigned* __restrict__ bar) {
    const int tid = blockIdx.x * blockDim.x + threadIdx.x;
    if (tid < BATCH) {
        float s = 0.f;
#pragma unroll
        for (int j = 0; j < WINDOW; ++j) s += y_real[tid * WINDOW + j] * w[j];
        yr_dot[tid] = s;
    }
    if (tid == 0) ctw[0] = 0.f;
    for (int i = tid; i < BAR_WORDS; i += 2048) bar[i] = 0u;
}

// ===========================================================================
// FALLBACK PATH (round-4 proven kernels, 3 launches/step)
// ===========================================================================
__global__ __launch_bounds__(256) void s1_mfma(const unsigned short* __restrict__ db,
                                               const unsigned short* __restrict__ sb,
                                               const unsigned short* __restrict__ Wdb,
                                               const unsigned short* __restrict__ Gtb,
                                               const float* __restrict__ vd,
                                               float* __restrict__ lpart) {
    __shared__ __align__(16) short As[64 * LDT];
    __shared__ __align__(16) short Bs[32 * LDT];
    __shared__ float red[2][64];
    const int tid = threadIdx.x;
    const int wave = tid >> 6, lane = tid & 63;
    const int wm = wave >> 1, wn = wave & 1;
    const int quad = lane >> 4, lr = lane & 15, qk = quad * 8;
    const int m0 = (blockIdx.x & 31) * 64;
    const int nb = blockIdx.x >> 5;
    const int n0 = nb * 32;
    const int arow = tid >> 2, aseg = tid & 3;
    floatx4 acc[2] = {};
#pragma unroll
    for (int pass = 0; pass < 2; ++pass) {
        const unsigned short* A = pass ? sb : db;
        const unsigned short* B = Wdb + pass * HIDDEN;
        for (int k0 = 0; k0 < HIDDEN; k0 += 32) {
            *(float4*)(As + arow * LDT + aseg * 8) =
                *(const float4*)(A + (size_t)(m0 + arow) * HIDDEN + k0 + aseg * 8);
            if (tid < 128)
                *(float4*)(Bs + arow * LDT + aseg * 8) =
                    *(const float4*)(B + (size_t)(n0 + arow) * (2 * HIDDEN) + k0 + aseg * 8);
            __syncthreads();
            short8 a0 = *(const short8*)(As + (wm * 32 + lr) * LDT + qk);
            short8 a1 = *(const short8*)(As + (wm * 32 + 16 + lr) * LDT + qk);
            short8 b  = *(const short8*)(Bs + (wn * 16 + lr) * LDT + qk);
            acc[0] = mfma16(a0, b, acc[0]);
            acc[1] = mfma16(a1, b, acc[1]);
            __syncthreads();
        }
    }
#pragma unroll
    for (int mf = 0; mf < 2; ++mf) {
        float rs[4];
#pragma unroll
        for (int r = 0; r < 4; ++r) {
            const int b = m0 + wm * 32 + mf * 16 + quad * 4 + r;
            const int i = n0 + wn * 16 + lr;
            float v = tanhf(acc[mf][r] + bf2f(Gtb[(size_t)b * HIDDEN + i])) * vd[i];
            for (int msk = 1; msk < 16; msk <<= 1) v += __shfl_xor(v, msk, 16);
            rs[r] = v;
        }
        if (lr == 0)
#pragma unroll
            for (int r = 0; r < 4; ++r)
                red[wn][wm * 32 + mf * 16 + quad * 4 + r] = rs[r];
    }
    __syncthreads();
    if (tid < 64)
        lpart[(size_t)nb * BATCH + m0 + tid] = red[0][tid] + red[1][tid];
}

__global__ void mid_kernel(const float* __restrict__ lpart, const float* __restrict__ hw_t,
                           float* __restrict__ ctw, const float* __restrict__ b00,
                           float* __restrict__ yscal, const float* __restrict__ yr_dot,
                           float* __restrict__ y_out) {
    __shared__ float sm[1024];
    __shared__ float sm2[1024];
    __shared__ float ysh;
    const int tid = threadIdx.x;  // 1024
    float l0 = 0.f, l1 = 0.f;
#pragma unroll
    for (int p = 0; p < 16; ++p) {
        l0 += lpart[p * BATCH + tid];
        l1 += lpart[p * BATCH + tid + 1024];
    }
    sm[tid] = fmaxf(l0, l1);
    __syncthreads();
    for (int off = 512; off; off >>= 1) {
        if (tid < off) sm[tid] = fmaxf(sm[tid], sm[tid + off]);
        __syncthreads();
    }
    const float M = sm[0];
    __syncthreads();
    const float e0 = expf(l0 - M), e1 = expf(l1 - M);
    sm[tid]  = e0 + e1;
    sm2[tid] = e0 * hw_t[tid] + e1 * hw_t[1024 + tid];
    __syncthreads();
    for (int off = 512; off; off >>= 1) {
        if (tid < off) { sm[tid] += sm[tid + off]; sm2[tid] += sm2[tid + off]; }
        __syncthreads();
    }
    if (tid == 0) {
        const float c = ctw[0] + sm2[0] / sm[0];
        ctw[0] = c;
        ysh = c + b00[0];
        yscal[0] = ysh;
    }
    __syncthreads();
    if (y_out != nullptr) {
        const float ys = ysh;
        y_out[tid]        = yr_dot[tid] + ys;
        y_out[1024 + tid] = yr_dot[1024 + tid] + ys;
    }
}

__global__ __launch_bounds__(256) void gates_lstm_mfma(
        const unsigned short* __restrict__ db, const unsigned short* __restrict__ Whhb,
        const float* __restrict__ Wih, const float* __restrict__ bih,
        const float* __restrict__ bhh, const float* __restrict__ yr_dot,
        const float* __restrict__ yscal, const float* __restrict__ s_old,
        float* __restrict__ s_new, float* __restrict__ d_new,
        unsigned short* __restrict__ sb_new, unsigned short* __restrict__ db_new) {
    __shared__ __align__(16) short As[64 * LDT];
    __shared__ __align__(16) short Bs[4][32 * LDT];
    const int tid = threadIdx.x;
    const int wave = tid >> 6, lane = tid & 63;
    const int wm = wave >> 1, wn = wave & 1;
    const int quad = lane >> 4, lr = lane & 15, qk = quad * 8;
    const int m0 = (blockIdx.x & 31) * 64;
    const int n0 = (blockIdx.x >> 5) * 32;
    const int arow = tid >> 2, aseg = tid & 3;
    floatx4 acc[4][2] = {};
    for (int k0 = 0; k0 < HIDDEN; k0 += 32) {
        *(float4*)(As + arow * LDT + aseg * 8) =
            *(const float4*)(db + (size_t)(m0 + arow) * HIDDEN + k0 + aseg * 8);
#pragma unroll
        for (int j = 0; j < 2; ++j) {
            const int c = tid + 256 * j;
            const int g = c >> 7, cc = c & 127, row = cc >> 2, seg = cc & 3;
            *(float4*)(Bs[g] + row * LDT + seg * 8) =
                *(const float4*)(Whhb + (size_t)(g * HIDDEN + n0 + row) * HIDDEN + k0 + seg * 8);
        }
        __syncthreads();
        short8 a0 = *(const short8*)(As + (wm * 32 + lr) * LDT + qk);
        short8 a1 = *(const short8*)(As + (wm * 32 + 16 + lr) * LDT + qk);
#pragma unroll
        for (int g = 0; g < 4; ++g) {
            short8 b = *(const short8*)(Bs[g] + (wn * 16 + lr) * LDT + qk);
            acc[g][0] = mfma16(a0, b, acc[g][0]);
            acc[g][1] = mfma16(a1, b, acc[g][1]);
        }
        __syncthreads();
    }
    const float ys = yscal[0];
    const int i = n0 + wn * 16 + lr;
    float wi[4], cb[4];
#pragma unroll
    for (int g = 0; g < 4; ++g) {
        wi[g] = Wih[g * HIDDEN + i];
        cb[g] = bih[g * HIDDEN + i] + bhh[g * HIDDEN + i];
    }
#pragma unroll
    for (int mf = 0; mf < 2; ++mf) {
#pragma unroll
        for (int r = 0; r < 4; ++r) {
            const int b = m0 + wm * 32 + mf * 16 + quad * 4 + r;
            const float yf = yr_dot[b] + ys;
            const size_t idx = (size_t)b * HIDDEN + i;
            const float ig = acc[0][mf][r] + yf * wi[0] + cb[0];
            const float fg = acc[1][mf][r] + yf * wi[1] + cb[1];
            const float gg = acc[2][mf][r] + yf * wi[2] + cb[2];
            const float og = acc[3][mf][r] + yf * wi[3] + cb[3];
            const float sn = sigmoidf(fg) * s_old[idx] + sigmoidf(ig) * tanhf(gg);
            const float dn = sigmoidf(og) * tanhf(sn);
            s_new[idx] = sn;
            sb_new[idx] = f2bf(sn);
            db_new[idx] = f2bf(dn);
            if (d_new != nullptr) d_new[idx] = dn;
        }
    }
}

// ===========================================================================
// COOPERATIVE PATH: persistent scan, 256 blocks, hierarchical XCD barrier.
// Block bx: m-tile = bx&31 (64 rows), n-tile = bx>>5 (64 cols).
// ===========================================================================
__global__ __launch_bounds__(256) void scan_coop(
        const unsigned short* __restrict__ dbb0, unsigned short* __restrict__ dbb1,
        const unsigned short* __restrict__ sbb0, unsigned short* __restrict__ sbb1,
        float* __restrict__ sbuf0, float* __restrict__ sbuf1,
        const float* __restrict__ s_init,
        const unsigned short* __restrict__ Wdb, const unsigned short* __restrict__ Whhb,
        const unsigned short* __restrict__ Gb, const float* __restrict__ vd,
        const float* __restrict__ Wih, const float* __restrict__ bih,
        const float* __restrict__ bhh, const float* __restrict__ yr_dot,
        const float* __restrict__ hw, const float* __restrict__ b00,
        float* __restrict__ lpart, float* __restrict__ y_out,
        float* __restrict__ d_out_f, float* __restrict__ s_out_f,
        unsigned* __restrict__ bar) {
    __shared__ __align__(16) short As[64 * LDT];
    __shared__ __align__(16) short Bwd[64 * LDT];
    __shared__ __align__(16) short Bwh[4][64 * LDT];
    __shared__ float red[2][64];
    __shared__ float smax[256], ssum[256], ssum2[256];
    __shared__ unsigned livemask[8];
    __shared__ int sh_pos, sh_closer;

    unsigned lgen = 0;

    const int tid = threadIdx.x;
    const int wave = tid >> 6, lane = tid & 63;
    const int wm = wave >> 1, wn = wave & 1;
    const int quad = lane >> 4, lr = lane & 15, qk = quad * 8;
    const int bx = blockIdx.x;
    const int m0 = (bx & 31) * 64;
    const int nt = bx >> 5;              // 0..7
    const int n0 = nt * 64;
    const int arow = tid >> 2, aseg = tid & 3;

    // ---- prologue: XCD discovery + closer election (one conservative barrier) ----
    unsigned* regc = bar + REG_OFF;
    unsigned* pbc  = bar + PB_OFF;
    unsigned* pbg  = bar + PB_OFF + 4;
    unsigned xcdreg;
    asm volatile("s_getreg_b32 %0, hwreg(HW_REG_XCC_ID)" : "=s"(xcdreg));
    const int my_xcd = (int)(xcdreg & 7u);
    if (tid == 0) sh_pos = (int)atomicAdd(&regc[my_xcd], 1u);
    __syncthreads();
    if (tid == 0) {
        __threadfence();
        if (atomicAdd(pbc, 1u) == GRIDB - 1u)
            __hip_atomic_store(pbg, 1u, __ATOMIC_RELEASE, __HIP_MEMORY_SCOPE_AGENT);
        else
            while (__hip_atomic_load(pbg, __ATOMIC_ACQUIRE, __HIP_MEMORY_SCOPE_AGENT) == 0u)
                __builtin_amdgcn_s_sleep(1);
        __threadfence();
        sh_closer = (sh_pos == (int)ld_rlx(&regc[my_xcd]) - 1) ? 1 : 0;
    }
    if (tid >= 8 && tid < 16) livemask[tid - 8] = 0u;  // placeholder ordering
    __syncthreads();
    if (tid < 8) livemask[tid] = (ld_rlx(&regc[tid]) > 0u) ? 1u : 0u;
    __syncthreads();
    const bool closer = (sh_closer != 0);

    const float b00v = b00[0];
    int icolv[2];
    float vdv[2], wi[4][2], cbv[4][2];
#pragma unroll
    for (int nf = 0; nf < 2; ++nf) {
        icolv[nf] = n0 + wn * 32 + nf * 16 + lr;
        vdv[nf] = vd[icolv[nf]];
#pragma unroll
        for (int g = 0; g < 4; ++g) {
            wi[g][nf]  = Wih[g * HIDDEN + icolv[nf]];
            cbv[g][nf] = bih[g * HIDDEN + icolv[nf]] + bhh[g * HIDDEN + icolv[nf]];
        }
    }
    float yrc[2][4];
#pragma unroll
    for (int mf = 0; mf < 2; ++mf)
#pragma unroll
        for (int r = 0; r < 4; ++r)
            yrc[mf][r] = yr_dot[m0 + wm * 32 + mf * 16 + quad * 4 + r];

    float ctw = 0.f;   // identical in every block (deterministic redundant compute)

    for (int t = 0; t < WINDOW; ++t) {
        const int rp = t & 1;
        const unsigned short* dcur = rp ? dbb1 : dbb0;
        const unsigned short* scur = rp ? sbb1 : sbb0;
        unsigned short* dnxt = rp ? (unsigned short*)dbb0 : dbb1;
        unsigned short* snxt = rp ? (unsigned short*)sbb0 : sbb1;
        const float* s_old = (t == 0) ? s_init : (rp ? sbuf0 : sbuf1);
        float* s_new = (t == WINDOW - 1) ? s_out_f : (rp ? sbuf1 : sbuf0);
        const unsigned short* Gtb = Gb + (size_t)t * BH;

        // ---------- Phase A: fused s1 (K=1024) + gates (K=512) GEMMs ----------
        floatx4 acc1[2][2] = {};
        floatx4 accg[4][2][2] = {};
        for (int k0 = 0; k0 < HIDDEN; k0 += 32) {
            *(float4*)(As + arow * LDT + aseg * 8) =
                *(const float4*)(dcur + (size_t)(m0 + arow) * HIDDEN + k0 + aseg * 8);
            *(float4*)(Bwd + arow * LDT + aseg * 8) =
                *(const float4*)(Wdb + (size_t)(n0 + arow) * (2 * HIDDEN) + k0 + aseg * 8);
#pragma unroll
            for (int j = 0; j < 4; ++j) {
                const int c = tid + 256 * j;          // 1024 chunks: 4g x 64row x 4seg
                const int g = c >> 8, cc = c & 255, row = cc >> 2, seg = cc & 3;
                *(float4*)(Bwh[g] + row * LDT + seg * 8) =
                    *(const float4*)(Whhb + (size_t)(g * HIDDEN + n0 + row) * HIDDEN + k0 + seg * 8);
            }
            __syncthreads();
            short8 a0  = *(const short8*)(As + (wm * 32 + lr) * LDT + qk);
            short8 a1  = *(const short8*)(As + (wm * 32 + 16 + lr) * LDT + qk);
            short8 bw0 = *(const short8*)(Bwd + (wn * 32 + lr) * LDT + qk);
            short8 bw1 = *(const short8*)(Bwd + (wn * 32 + 16 + lr) * LDT + qk);
            acc1[0][0] = mfma16(a0, bw0, acc1[0][0]);
            acc1[0][1] = mfma16(a0, bw1, acc1[0][1]);
            acc1[1][0] = mfma16(a1, bw0, acc1[1][0]);
            acc1[1][1] = mfma16(a1, bw1, acc1[1][1]);
#pragma unroll
            for (int g = 0; g < 4; ++g) {
                short8 bh0 = *(const short8*)(Bwh[g] + (wn * 32 + lr) * LDT + qk);
                short8 bh1 = *(const short8*)(Bwh[g] + (wn * 32 + 16 + lr) * LDT + qk);
                accg[g][0][0] = mfma16(a0, bh0, accg[g][0][0]);
                accg[g][0][1] = mfma16(a0, bh1, accg[g][0][1]);
                accg[g][1][0] = mfma16(a1, bh0, accg[g][1][0]);
                accg[g][1][1] = mfma16(a1, bh1, accg[g][1][1]);
            }
            __syncthreads();
        }
        // pass 1: A = s0, Wd cols [512,1024) (s1 only)
        for (int k0 = 0; k0 < HIDDEN; k0 += 32) {
            *(float4*)(As + arow * LDT + aseg * 8) =
                *(const float4*)(scur + (size_t)(m0 + arow) * HIDDEN + k0 + aseg * 8);
            *(float4*)(Bwd + arow * LDT + aseg * 8) =
                *(const float4*)(Wdb + (size_t)(n0 + arow) * (2 * HIDDEN) + HIDDEN + k0 + aseg * 8);
            __syncthreads();
            short8 a0  = *(const short8*)(As + (wm * 32 + lr) * LDT + qk);
            short8 a1  = *(const short8*)(As + (wm * 32 + 16 + lr) * LDT + qk);
            short8 bw0 = *(const short8*)(Bwd + (wn * 32 + lr) * LDT + qk);
            short8 bw1 = *(const short8*)(Bwd + (wn * 32 + 16 + lr) * LDT + qk);
            acc1[0][0] = mfma16(a0, bw0, acc1[0][0]);
            acc1[0][1] = mfma16(a0, bw1, acc1[0][1]);
            acc1[1][0] = mfma16(a1, bw0, acc1[1][0]);
            acc1[1][1] = mfma16(a1, bw1, acc1[1][1]);
            __syncthreads();
        }
        // s1 epilogue: tanh(.+Gt)*vd, reduce over this block's 64 cols
#pragma unroll
        for (int mf = 0; mf < 2; ++mf) {
            float rs[4];
#pragma unroll
            for (int r = 0; r < 4; ++r) {
                const int b = m0 + wm * 32 + mf * 16 + quad * 4 + r;
                float v = 0.f;
#pragma unroll
                for (int nf = 0; nf < 2; ++nf)
                    v += tanhf(acc1[mf][nf][r] + bf2f(Gtb[(size_t)b * HIDDEN + icolv[nf]])) * vdv[nf];
                for (int msk = 1; msk < 16; msk <<= 1) v += __shfl_xor(v, msk, 16);
                rs[r] = v;
            }
            if (lr == 0)
#pragma unroll
                for (int r = 0; r < 4; ++r)
                    red[wn][wm * 32 + mf * 16 + quad * 4 + r] = rs[r];
        }
        __syncthreads();
        if (tid < 64)
            lpart[(size_t)nt * BATCH + m0 + tid] = red[0][tid] + red[1][tid];

        xbarrier(bar, livemask, bx, my_xcd, closer, lgen);

        // ---------- Phase B: redundant softmax + ctw recursion ----------
        const int bb = tid * 8;
        float l[8] = {0.f, 0.f, 0.f, 0.f, 0.f, 0.f, 0.f, 0.f};
#pragma unroll
        for (int p = 0; p < 8; ++p) {
            const float4 u0 = *(const float4*)(lpart + (size_t)p * BATCH + bb);
            const float4 u1 = *(const float4*)(lpart + (size_t)p * BATCH + bb + 4);
            l[0] += u0.x; l[1] += u0.y; l[2] += u0.z; l[3] += u0.w;
            l[4] += u1.x; l[5] += u1.y; l[6] += u1.z; l[7] += u1.w;
        }
        float mx = l[0];
#pragma unroll
        for (int j = 1; j < 8; ++j) mx = fmaxf(mx, l[j]);
        smax[tid] = mx;
        __syncthreads();
        for (int o = 128; o; o >>= 1) {
            if (tid < o) smax[tid] = fmaxf(smax[tid], smax[tid + o]);
            __syncthreads();
        }
        const float M = smax[0];
        const float* hwt = hw + (size_t)t * BATCH;
        const float4 h0 = *(const float4*)(hwt + bb);
        const float4 h1 = *(const float4*)(hwt + bb + 4);
        const float hv[8] = {h0.x, h0.y, h0.z, h0.w, h1.x, h1.y, h1.z, h1.w};
        float se = 0.f, sh = 0.f;
#pragma unroll
        for (int j = 0; j < 8; ++j) {
            const float e = expf(l[j] - M);
            se += e;
            sh += e * hv[j];
        }
        ssum[tid] = se; ssum2[tid] = sh;
        __syncthreads();
        for (int o = 128; o; o >>= 1) {
            if (tid < o) { ssum[tid] += ssum[tid + o]; ssum2[tid] += ssum2[tid + o]; }
            __syncthreads();
        }
        ctw += ssum2[0] / ssum[0];
        const float ys = ctw + b00v;

        // ---------- Phase C: gates epilogue + LSTM update ----------
#pragma unroll
        for (int nf = 0; nf < 2; ++nf) {
#pragma unroll
            for (int mf = 0; mf < 2; ++mf) {
#pragma unroll
                for (int r = 0; r < 4; ++r) {
                    const int b = m0 + wm * 32 + mf * 16 + quad * 4 + r;
                    const float yf = yrc[mf][r] + ys;
                    const size_t idx = (size_t)b * HIDDEN + icolv[nf];
                    const float ig = accg[0][mf][nf][r] + yf * wi[0][nf] + cbv[0][nf];
                    const float fg = accg[1][mf][nf][r] + yf * wi[1][nf] + cbv[1][nf];
                    const float gg = accg[2][mf][nf][r] + yf * wi[2][nf] + cbv[2][nf];
                    const float og = accg[3][mf][nf][r] + yf * wi[3][nf] + cbv[3][nf];
                    const float sn = sigmoidf(fg) * s_old[idx] + sigmoidf(ig) * tanhf(gg);
                    const float dn = sigmoidf(og) * tanhf(sn);
                    s_new[idx] = sn;
                    snxt[idx] = f2bf(sn);
                    dnxt[idx] = f2bf(dn);
                    if (t == WINDOW - 1) d_out_f[idx] = dn;
                }
            }
        }
        if (t == WINDOW - 1 && nt == 0 && tid < 64)
            y_out[m0 + tid] = yr_dot[m0 + tid] + ys;

        xbarrier(bar, livemask, bx, my_xcd, closer, lgen);
    }
}

// ---------------------------------------------------------------------------
extern "C" void kernel_launch(void* const* d_in, const int* in_sizes, int n_in,
                              void* d_out, int out_size, void* d_ws, size_t ws_size,
                              hipStream_t stream) {
    const float* Z      = (const float*)d_in[0];
    const float* d_init = (const float*)d_in[1];
    const float* s_init = (const float*)d_in[2];
    const float* y_real = (const float*)d_in[3];
    const float* vd     = (const float*)d_in[4];
    const float* Wd     = (const float*)d_in[5];
    const float* Ud     = (const float*)d_in[6];
    const float* w      = (const float*)d_in[7];
    const float* b00    = (const float*)d_in[8];
    const float* conv_w = (const float*)d_in[9];
    const float* conv_b = (const float*)d_in[10];
    const float* Wih    = (const float*)d_in[11];
    const float* Whh    = (const float*)d_in[12];
    const float* bih    = (const float*)d_in[13];
    const float* bhh    = (const float*)d_in[14];

    float* ws = (float*)d_ws;
    size_t off = 0;
    unsigned short* Htb = (unsigned short*)(ws + off);  off += (size_t)WINDOW * BH / 2;
    unsigned short* Gb  = (unsigned short*)(ws + off);  off += (size_t)WINDOW * BH / 2;
    unsigned short* dbb0 = (unsigned short*)(ws + off);  off += BH / 2;
    unsigned short* dbb1 = (unsigned short*)(ws + off);  off += BH / 2;
    unsigned short* sbb0 = (unsigned short*)(ws + off);  off += BH / 2;
    unsigned short* sbb1 = (unsigned short*)(ws + off);  off += BH / 2;
    float* sbuf0 = ws + off;  off += BH;
    float* sbuf1 = ws + off;  off += BH;
    unsigned short* Wdb  = (unsigned short*)(ws + off);  off += (size_t)HIDDEN * 2 * HIDDEN / 2;
    unsigned short* Udb  = (unsigned short*)(ws + off);  off += (size_t)HIDDEN * HIDDEN / 2;
    unsigned short* Whhb = (unsigned short*)(ws + off);  off += (size_t)H4 * HIDDEN / 2;
    float* hw     = ws + off;  off += (size_t)WINDOW * BATCH;
    float* lpart  = ws + off;  off += (size_t)16 * BATCH;
    float* yr_dot = ws + off;  off += BATCH;
    float* ctw    = ws + off;  off += 4;
    float* yscal  = ws + off;  off += 4;
    unsigned* bar = (unsigned*)(ws + off);  off += BAR_WORDS;

    float* out = (float*)d_out;
    float* y_out   = out;
    float* d_out_f = out + BATCH;
    float* s_out_f = out + BATCH + (size_t)BH;

    // --- one-time prep ---
    cvt5_kernel<<<3840, 256, 0, stream>>>(Wd, Wdb, Ud, Udb, Whh, Whhb,
                                          d_init, dbb0, s_init, sbb0);
    conv_kernel<<<BATCH, 256, 0, stream>>>(Z, conv_w, conv_b, (unsigned int*)Htb);
    hw_kernel<<<(WINDOW * BATCH) / 4, 256, 0, stream>>>(Htb, w, hw);
    {
        dim3 grid(HIDDEN / 64, (WINDOW * BATCH) / 64);
        g_gemm_mfma<<<grid, 256, 0, stream>>>(Htb, Udb, Gb);
    }
    init_kernel<<<8, 256, 0, stream>>>(y_real, w, yr_dot, ctw, bar);

    // --- cooperative persistent scan (256 blocks, hierarchical XCD barrier) ---
    const unsigned short* dbb0c = dbb0;
    const unsigned short* sbb0c = sbb0;
    void* args[] = {
        (void*)&dbb0c, (void*)&dbb1, (void*)&sbb0c, (void*)&sbb1,
        (void*)&sbuf0, (void*)&sbuf1, (void*)&s_init,
        (void*)&Wdb, (void*)&Whhb, (void*)&Gb, (void*)&vd,
        (void*)&Wih, (void*)&bih, (void*)&bhh, (void*)&yr_dot,
        (void*)&hw, (void*)&b00, (void*)&lpart, (void*)&y_out,
        (void*)&d_out_f, (void*)&s_out_f, (void*)&bar,
    };
    hipError_t cerr = hipLaunchCooperativeKernel((void*)scan_coop, dim3(GRIDB), dim3(256),
                                                 args, 0, stream);
    if (cerr != hipSuccess) {
        (void)hipGetLastError();   // clear sticky error state
        // --- fallback: proven round-4 3-launch scan ---
        const float* s_read = s_init;
        int pp = 0;
        for (int t = 0; t < WINDOW; ++t) {
            const unsigned short* Gtb = Gb + (size_t)t * BH;
            unsigned short* dbbs[2] = {dbb0, dbb1};
            unsigned short* sbbs[2] = {sbb0, sbb1};
            float* sbufs[2] = {sbuf0, sbuf1};
            s1_mfma<<<512, 256, 0, stream>>>(dbbs[pp], sbbs[pp], Wdb, Gtb, vd, lpart);
            mid_kernel<<<1, 1024, 0, stream>>>(lpart, hw + t * BATCH, ctw, b00, yscal,
                                               yr_dot, (t == WINDOW - 1) ? y_out : nullptr);
            float* s_w = (t == WINDOW - 1) ? s_out_f : sbufs[t & 1];
            float* d_w = (t == WINDOW - 1) ? d_out_f : nullptr;
            gates_lstm_mfma<<<512, 256, 0, stream>>>(dbbs[pp], Whhb, Wih, bih, bhh,
                                                     yr_dot, yscal, s_read, s_w, d_w,
                                                     sbbs[1 - pp], dbbs[1 - pp]);
            s_read = s_w;
            pp ^= 1;
        }
    }
}